// Round 3
// baseline (928.920 us; speedup 1.0000x reference)
//
#include <hip/hip_runtime.h>
#include <cstdint>
#include <cstddef>

#define L_DIM 4096
#define D_DIM 512
#define CIN   256
#define BATCH 16
#define KSPLIT 4
#define CANDMAX 2048
#define CAND_MARGIN 0.06f

typedef _Float16 half8 __attribute__((ext_vector_type(8)));
typedef unsigned short ushort8 __attribute__((ext_vector_type(8)));
typedef float f32x4 __attribute__((ext_vector_type(4)));

__device__ __forceinline__ void gld16(const _Float16* g, _Float16* l) {
    __builtin_amdgcn_global_load_lds(
        (const __attribute__((address_space(1))) unsigned int*)g,
        (__attribute__((address_space(3))) unsigned int*)l,
        16, 0, 0);
}

// ---------------------------------------------------------------------------
// Split W (3 x 512x512 fp32) into fp16 hi/lo. grid (1024,3), block 256
// ---------------------------------------------------------------------------
__global__ __launch_bounds__(256) void convert_w(
    const float* __restrict__ Wq, const float* __restrict__ Wk,
    const float* __restrict__ Wv,
    _Float16* __restrict__ Wh, _Float16* __restrict__ Wl)
{
    const int w = blockIdx.y;
    const float* src = (w == 0) ? Wq : (w == 1) ? Wk : Wv;
    int i = blockIdx.x * 256 + threadIdx.x;
    float xv = src[i];
    _Float16 hi = (_Float16)xv;
    Wh[(size_t)w * 262144 + i] = hi;
    Wl[(size_t)w * 262144 + i] = (_Float16)(xv - (float)hi);
}

// ---------------------------------------------------------------------------
// Transpose + split X. Per phase 8 batches. grid (64, 8, 8), block 256.
// ---------------------------------------------------------------------------
__global__ __launch_bounds__(256) void convert_x(
    const float* __restrict__ x1, const float* __restrict__ x2,
    _Float16* __restrict__ XTh, _Float16* __restrict__ XTl, int phase)
{
    const int bb = blockIdx.z;
    const int b = phase * 8 + bb;
    const int s0 = blockIdx.x * 64;
    const int c0 = blockIdx.y * 64;
    __shared__ float t[64][65];
    const int tid = threadIdx.x;
    const int g = tid >> 6, sy = tid & 63;
    const float* src = (c0 < CIN)
        ? (x1 + (size_t)b * CIN * L_DIM + (size_t)c0 * L_DIM)
        : (x2 + (size_t)b * CIN * L_DIM + (size_t)(c0 - CIN) * L_DIM);
    #pragma unroll
    for (int r = 0; r < 16; r++) {
        int cl = g * 16 + r;
        t[cl][sy] = src[(size_t)cl * L_DIM + s0 + sy];
    }
    __syncthreads();
    _Float16* outh = XTh + (size_t)bb * L_DIM * 512 + (size_t)s0 * 512 + c0;
    _Float16* outl = XTl + (size_t)bb * L_DIM * 512 + (size_t)s0 * 512 + c0;
    #pragma unroll
    for (int r = 0; r < 16; r++) {
        int sl = g * 16 + r;
        float xv = t[sy][sl];
        _Float16 hi = (_Float16)xv;
        float lo = xv - (float)hi;
        outh[(size_t)sl * 512 + sy] = hi;
        outl[(size_t)sl * 512 + sy] = (_Float16)lo;
    }
}

// ---------------------------------------------------------------------------
// q/k projection, K-stacked x3 (K'=1536: Wh*Xh | Wl*Xh | Wh*Xl), 256x256
// tile, BK=32, depth-2 counted-vmcnt pipeline over 3 LDS buffers (96 KB).
// Raw s_barrier (no vmcnt(0) drain); vmcnt(8) keeps 2 tiles in flight.
// grid: (16 n-tiles, 2 m-tiles, 16 z), block 512 (8 waves, 2M x 4N).
// ---------------------------------------------------------------------------
__global__ __launch_bounds__(512, 2) void proj_qk_pipe(
    const _Float16* __restrict__ Wh, const _Float16* __restrict__ Wl,
    const _Float16* __restrict__ XTh, const _Float16* __restrict__ XTl,
    const float* __restrict__ bq, const float* __restrict__ bk,
    _Float16* __restrict__ qh, _Float16* __restrict__ ql,
    _Float16* __restrict__ kh, _Float16* __restrict__ kl,
    int phase)
{
    const int z = blockIdx.z;
    const int bb = z >> 1, w = z & 1;
    const int b = phase * 8 + bb;
    const _Float16* Ah_g = Wh + (size_t)w * 262144;
    const _Float16* Al_g = Wl + (size_t)w * 262144;
    const _Float16* Bh_g = XTh + (size_t)bb * ((size_t)L_DIM * 512);
    const _Float16* Bl_g = XTl + (size_t)bb * ((size_t)L_DIM * 512);
    const float* bias = (w == 0) ? bq : bk;
    _Float16* outh = ((w == 0) ? qh : kh) + (size_t)b * ((size_t)D_DIM * L_DIM);
    _Float16* outl = ((w == 0) ? ql : kl) + (size_t)b * ((size_t)D_DIM * L_DIM);

    const int m0 = blockIdx.y * 256;
    const int n0 = blockIdx.x * 256;

    __shared__ _Float16 lds[3 * 16384];   // 3 x (A[256][32] | B[256][32]) = 96 KB

    const int tid = threadIdx.x;
    const int lane = tid & 63;
    const int w8 = tid >> 6;
    const int lr = lane & 15, quad = lane >> 4;
    const int wr = w8 >> 2, wc = w8 & 3;
    const int qsw = (quad ^ ((lr >> 1) & 3)) * 8;

    // stage geometry: 2 chunks of A + 2 of B per thread per K-tile
    const int q0 = tid, q1 = tid + 512;
    const int r0 = q0 >> 2, s0_ = ((q0 & 3) ^ ((r0 >> 1) & 3)) * 8;
    const int r1 = q1 >> 2, s1_ = ((q1 & 3) ^ ((r1 >> 1) & 3)) * 8;
    const size_t a0off = (size_t)(m0 + r0) * 512 + s0_;
    const size_t a1off = (size_t)(m0 + r1) * 512 + s1_;
    const size_t b0off = (size_t)(n0 + r0) * 512 + s0_;
    const size_t b1off = (size_t)(n0 + r1) * 512 + s1_;

    f32x4 acc[8][4] = {};

#define STAGE(tt)                                                         \
    {                                                                     \
        const int pc_ = (tt) >> 4;                                        \
        const int kk_ = ((tt) & 15) * 32;                                 \
        const _Float16* As_ = (pc_ == 1) ? Al_g : Ah_g;                   \
        const _Float16* Bs_ = (pc_ == 2) ? Bl_g : Bh_g;                   \
        _Float16* dst_ = lds + ((tt) % 3) * 16384;                        \
        gld16(As_ + a0off + kk_, dst_ + q0 * 8);                          \
        gld16(As_ + a1off + kk_, dst_ + q1 * 8);                          \
        gld16(Bs_ + b0off + kk_, dst_ + 8192 + q0 * 8);                   \
        gld16(Bs_ + b1off + kk_, dst_ + 8192 + q1 * 8);                   \
    }

    STAGE(0);
    STAGE(1);

    const int NT = 48;    // 1536 / 32
    for (int kt = 0; kt < NT; kt++) {
        if (kt + 2 < NT) STAGE(kt + 2);
        if (kt + 2 < NT)      asm volatile("s_waitcnt vmcnt(8)" ::: "memory");
        else if (kt + 1 < NT) asm volatile("s_waitcnt vmcnt(4)" ::: "memory");
        else                  asm volatile("s_waitcnt vmcnt(0)" ::: "memory");
        __builtin_amdgcn_sched_barrier(0);
        __builtin_amdgcn_s_barrier();
        __builtin_amdgcn_sched_barrier(0);

        const _Float16* bufA = lds + (kt % 3) * 16384;
        const _Float16* bufB = bufA + 8192;
        half8 fA[8], fB[4];
        #pragma unroll
        for (int i = 0; i < 8; i++)
            fA[i] = *(const half8*)(bufA + (wr * 128 + i * 16 + lr) * 32 + qsw);
        #pragma unroll
        for (int j = 0; j < 4; j++)
            fB[j] = *(const half8*)(bufB + (wc * 64 + j * 16 + lr) * 32 + qsw);

        __builtin_amdgcn_s_setprio(1);
        #pragma unroll
        for (int j = 0; j < 4; j++)
            #pragma unroll
            for (int i = 0; i < 8; i++)
                acc[i][j] = __builtin_amdgcn_mfma_f32_16x16x32_f16(fA[i], fB[j], acc[i][j], 0, 0, 0);
        __builtin_amdgcn_s_setprio(0);

        __builtin_amdgcn_sched_barrier(0);
        __builtin_amdgcn_s_barrier();
        __builtin_amdgcn_sched_barrier(0);
    }
#undef STAGE

    #pragma unroll
    for (int i = 0; i < 8; i++) {
        int mg = m0 + wr * 128 + i * 16 + quad * 4;
        #pragma unroll
        for (int r = 0; r < 4; r++) {
            float bvv = bias[mg + r];
            #pragma unroll
            for (int j = 0; j < 4; j++) {
                int ng = n0 + wc * 64 + j * 16 + lr;
                float val = acc[i][j][r] + bvv;
                _Float16 hi = (_Float16)val;
                size_t off = (size_t)(mg + r) * L_DIM + ng;
                outh[off] = hi;
                outl[off] = (_Float16)(val - (float)hi);
            }
        }
    }
}

// ---------------------------------------------------------------------------
// V projection: hi-only single-MFMA GEMM. grid: (32, 4, 8), block 256
// ---------------------------------------------------------------------------
__global__ __launch_bounds__(256) void proj_mfma_v(
    const _Float16* __restrict__ Wh, const _Float16* __restrict__ XTh,
    const float* __restrict__ bv, _Float16* __restrict__ vh, int phase)
{
    const int bb = blockIdx.z;
    const int b = phase * 8 + bb;
    const _Float16* Ah_g = Wh + (size_t)2 * 262144;
    const _Float16* Bh_g = XTh + (size_t)bb * ((size_t)L_DIM * 512);
    _Float16* outh = vh + (size_t)b * ((size_t)D_DIM * L_DIM);

    const int m0 = blockIdx.y * 128;
    const int n0 = blockIdx.x * 128;

    __shared__ _Float16 lds[2 * 128 * 32];
    _Float16* ldsA_h = lds;
    _Float16* ldsB_h = lds + 4096;

    const int tid = threadIdx.x;
    const int w4 = tid >> 6, lane = tid & 63;
    const int lr = lane & 15, quad = lane >> 4;
    const int wr = w4 >> 1, wc = w4 & 1;

    f32x4 acc[4][4] = {};

    const int q1 = w4 * 128 + lane, q2 = q1 + 64;
    const int r1 = q1 >> 2, c41 = (q1 & 3) ^ ((r1 >> 1) & 3);
    const int r2 = q2 >> 2, c42 = (q2 & 3) ^ ((r2 >> 1) & 3);

    const _Float16* pAh1 = Ah_g + (size_t)(m0 + r1) * 512 + c41 * 8;
    const _Float16* pAh2 = Ah_g + (size_t)(m0 + r2) * 512 + c42 * 8;
    const _Float16* pBh1 = Bh_g + (size_t)(n0 + r1) * 512 + c41 * 8;
    const _Float16* pBh2 = Bh_g + (size_t)(n0 + r2) * 512 + c42 * 8;

    _Float16* d1 = (_Float16*)(lds) + (size_t)(w4 * 128) * 8;
    _Float16* d2 = (_Float16*)(lds) + (size_t)(w4 * 128 + 64) * 8;

    const int qsw = (quad ^ ((lr >> 1) & 3)) * 8;

    for (int k0 = 0; k0 < 512; k0 += 32) {
        if (k0) __syncthreads();
        gld16(pAh1 + k0, d1);
        gld16(pAh2 + k0, d2);
        gld16(pBh1 + k0, d1 + 4096);
        gld16(pBh2 + k0, d2 + 4096);
        __syncthreads();

        half8 fAh[4];
        #pragma unroll
        for (int i = 0; i < 4; i++) {
            int m = wr * 64 + i * 16 + lr;
            fAh[i] = *(const half8*)(ldsA_h + m * 32 + qsw);
        }
        #pragma unroll
        for (int j = 0; j < 4; j++) {
            int n = wc * 64 + j * 16 + lr;
            half8 fBh = *(const half8*)(ldsB_h + n * 32 + qsw);
            #pragma unroll
            for (int i = 0; i < 4; i++)
                acc[i][j] = __builtin_amdgcn_mfma_f32_16x16x32_f16(fAh[i], fBh, acc[i][j], 0, 0, 0);
        }
    }

    #pragma unroll
    for (int i = 0; i < 4; i++) {
        int mg = m0 + wr * 64 + i * 16 + quad * 4;
        #pragma unroll
        for (int r = 0; r < 4; r++) {
            float bvv = bv[mg + r];
            #pragma unroll
            for (int j = 0; j < 4; j++) {
                int ng = n0 + wc * 64 + j * 16 + lr;
                outh[(size_t)(mg + r) * L_DIM + ng] = (_Float16)(acc[i][j][r] + bvv);
            }
        }
    }
}

// ---------------------------------------------------------------------------
// Stage A: qks with hi-only x1 MFMA (candidate pre-selection only).
// grid: (32 l-tiles, nst s-tiles, 16 b), block 256
// ---------------------------------------------------------------------------
__global__ __launch_bounds__(256) void qks_x1(
    const _Float16* __restrict__ qh, const _Float16* __restrict__ kh,
    const int* __restrict__ idx_sample,
    float* __restrict__ Mmax, float* __restrict__ Msum, int U, int nst)
{
    const int b = blockIdx.z;
    const int stile = blockIdx.y;
    const int l0 = blockIdx.x * 128;
    const int s0 = stile * 128;
    const size_t perB = (size_t)D_DIM * L_DIM;
    const _Float16* qh_b = qh + (size_t)b * perB;
    const _Float16* kh_b = kh + (size_t)b * perB;

    __shared__ _Float16 ldsAh[4096];   // gathered k [s][32]
    __shared__ _Float16 ldsBh[4096];   // q [l][32]
    __shared__ int sidx[128];
    __shared__ float redm[8][128];
    __shared__ float reds[8][128];

    const int tid = threadIdx.x;
    const int w4 = tid >> 6, lane = tid & 63;
    const int lr = lane & 15, quad = lane >> 4;
    const int ws = w4 >> 1, wl = w4 & 1;

    if (tid < 128) {
        int s = s0 + tid;
        sidx[tid] = (s < U) ? idx_sample[s] : idx_sample[0];
    }
    __syncthreads();

    f32x4 acc[4][4] = {};
    const int qsw = (quad ^ ((lr >> 1) & 3)) * 8;

    for (int k0 = 0; k0 < 512; k0 += 32) {
        #pragma unroll
        for (int t = 0; t < 2; t++) {
            int c = w4 * 128 + t * 64 + lane;
            int row = c >> 2, part = (c & 3) ^ ((row >> 1) & 3);
            int krow = sidx[row];
            size_t go = (size_t)krow * 512 + k0 + part * 8;
            size_t qo = (size_t)(l0 + row) * 512 + k0 + part * 8;
            int base = (w4 * 128 + t * 64) * 8;
            gld16(kh_b + go, ldsAh + base);
            gld16(qh_b + qo, ldsBh + base);
        }
        __syncthreads();

        half8 fAh[4];
        #pragma unroll
        for (int i = 0; i < 4; i++) {
            int s = ws * 64 + i * 16 + lr;
            fAh[i] = *(const half8*)(ldsAh + s * 32 + qsw);
        }
        #pragma unroll
        for (int j = 0; j < 4; j++) {
            int l = wl * 64 + j * 16 + lr;
            half8 fBh = *(const half8*)(ldsBh + l * 32 + qsw);
            #pragma unroll
            for (int i = 0; i < 4; i++)
                acc[i][j] = __builtin_amdgcn_mfma_f32_16x16x32_f16(fAh[i], fBh, acc[i][j], 0, 0, 0);
        }
        __syncthreads();
    }

    float runmax[4], runsum[4];
    #pragma unroll
    for (int j = 0; j < 4; j++) { runmax[j] = -__builtin_inff(); runsum[j] = 0.f; }
    #pragma unroll
    for (int i = 0; i < 4; i++) {
        #pragma unroll
        for (int r = 0; r < 4; r++) {
            int sg = s0 + ws * 64 + i * 16 + quad * 4 + r;
            if (sg < U) {
                #pragma unroll
                for (int j = 0; j < 4; j++) {
                    runmax[j] = fmaxf(runmax[j], acc[i][j][r]);
                    runsum[j] += acc[i][j][r];
                }
            }
        }
    }
    #pragma unroll
    for (int j = 0; j < 4; j++) {
        int l = wl * 64 + j * 16 + lr;
        redm[ws * 4 + quad][l] = runmax[j];
        reds[ws * 4 + quad][l] = runsum[j];
    }
    __syncthreads();
    if (tid < 128) {
        float gm = -__builtin_inff(), gs = 0.f;
        #pragma unroll
        for (int t = 0; t < 8; t++) { gm = fmaxf(gm, redm[t][tid]); gs += reds[t][tid]; }
        size_t o = ((size_t)b * nst + stile) * L_DIM + l0 + tid;
        Mmax[o] = gm;
        Msum[o] = gs;
    }
}

// ---------------------------------------------------------------------------
// Candidate selection with margin. grid (B), block 512.
// ---------------------------------------------------------------------------
__global__ __launch_bounds__(512) void topk_cand(
    const float* __restrict__ Mmax, const float* __restrict__ Msum,
    int* __restrict__ candlist, int* __restrict__ ncand, int U, int nst)
{
    const int b = blockIdx.x;
    const int tid = threadIdx.x;
    __shared__ int wcnt[8];
    __shared__ int basec;

    float Mv[8];
    unsigned mykey[8];
    #pragma unroll
    for (int t = 0; t < 8; t++) {
        int l = t * 512 + tid;
        float gm = -__builtin_inff(), gs = 0.f;
        for (int st = 0; st < nst; st++) {
            size_t o = ((size_t)b * nst + st) * L_DIM + l;
            gm = fmaxf(gm, Mmax[o]);
            gs += Msum[o];
        }
        float M = gm - gs * (1.f / (float)L_DIM);
        Mv[t] = M;
        unsigned bits = __float_as_uint(M);
        mykey[t] = (bits & 0x80000000u) ? ~bits : (bits | 0x80000000u);
    }
    if (tid == 0) basec = 0;

    const int wv = tid >> 6, lane = tid & 63;
    unsigned lo = 0u, hi = 0xFFFFFFFFu;
    while (lo < hi) {
        unsigned hl = hi - lo;
        unsigned mid = lo + (hl >> 1) + (hl & 1u);
        int c = 0;
        #pragma unroll
        for (int t = 0; t < 8; t++) c += (mykey[t] >= mid) ? 1 : 0;
        #pragma unroll
        for (int o = 32; o > 0; o >>= 1) c += __shfl_down(c, o, 64);
        if (lane == 0) wcnt[wv] = c;
        __syncthreads();
        int total = 0;
        #pragma unroll
        for (int i = 0; i < 8; i++) total += wcnt[i];
        if (total >= U) lo = mid; else hi = mid - 1;
        __syncthreads();
    }
    unsigned tb = (lo & 0x80000000u) ? (lo & 0x7FFFFFFFu) : ~lo;
    float Tval = __uint_as_float(tb) - CAND_MARGIN;
    #pragma unroll
    for (int t = 0; t < 8; t++) {
        if (Mv[t] >= Tval) {
            int pos = atomicAdd(&basec, 1);
            if (pos < CANDMAX) candlist[b * CANDMAX + pos] = t * 512 + tid;
        }
    }
    __syncthreads();
    if (tid == 0) ncand[b] = (basec < CANDMAX) ? basec : CANDMAX;
}

// ---------------------------------------------------------------------------
// Refine: full fp16x3 qks over candidate rows only.
// grid: (CANDMAX/128, nst, 16 b), block 256; blocks beyond ncand exit.
// ---------------------------------------------------------------------------
__global__ __launch_bounds__(256) void refine_mfma(
    const _Float16* __restrict__ qh, const _Float16* __restrict__ ql,
    const _Float16* __restrict__ kh, const _Float16* __restrict__ kl,
    const int* __restrict__ idx_sample, const int* __restrict__ candlist,
    const int* __restrict__ ncand,
    float* __restrict__ Rmax, float* __restrict__ Rsum, int U, int nst)
{
    const int b = blockIdx.z;
    const int nc = ncand[b];
    const int c0 = blockIdx.x * 128;
    if (c0 >= nc) return;
    const int stile = blockIdx.y;
    const int s0 = stile * 128;
    const size_t perB = (size_t)D_DIM * L_DIM;
    const _Float16* qh_b = qh + (size_t)b * perB;
    const _Float16* ql_b = ql + (size_t)b * perB;
    const _Float16* kh_b = kh + (size_t)b * perB;
    const _Float16* kl_b = kl + (size_t)b * perB;

    __shared__ _Float16 ldsAh[4096], ldsAl[4096];
    __shared__ _Float16 ldsBh[4096], ldsBl[4096];
    __shared__ int sidx[128];
    __shared__ int crow[128];
    __shared__ float redm[8][128];
    __shared__ float reds[8][128];

    const int tid = threadIdx.x;
    const int w4 = tid >> 6, lane = tid & 63;
    const int lr = lane & 15, quad = lane >> 4;
    const int ws = w4 >> 1, wl = w4 & 1;

    if (tid < 128) {
        int s = s0 + tid;
        sidx[tid] = (s < U) ? idx_sample[s] : idx_sample[0];
        int c = c0 + tid;
        crow[tid] = candlist[b * CANDMAX + (c < nc ? c : 0)];
    }
    __syncthreads();

    f32x4 acc[4][4] = {};
    const int qsw = (quad ^ ((lr >> 1) & 3)) * 8;

    for (int k0 = 0; k0 < 512; k0 += 32) {
        #pragma unroll
        for (int t = 0; t < 2; t++) {
            int c = w4 * 128 + t * 64 + lane;
            int row = c >> 2, part = (c & 3) ^ ((row >> 1) & 3);
            int krow = sidx[row];
            size_t go = (size_t)krow * 512 + k0 + part * 8;
            size_t qo = (size_t)crow[row] * 512 + k0 + part * 8;
            int base = (w4 * 128 + t * 64) * 8;
            gld16(kh_b + go, ldsAh + base);
            gld16(kl_b + go, ldsAl + base);
            gld16(qh_b + qo, ldsBh + base);
            gld16(ql_b + qo, ldsBl + base);
        }
        __syncthreads();

        half8 fAh[4], fAl[4];
        #pragma unroll
        for (int i = 0; i < 4; i++) {
            int s = ws * 64 + i * 16 + lr;
            fAh[i] = *(const half8*)(ldsAh + s * 32 + qsw);
            fAl[i] = *(const half8*)(ldsAl + s * 32 + qsw);
        }
        #pragma unroll
        for (int j = 0; j < 4; j++) {
            int l = wl * 64 + j * 16 + lr;
            half8 fBh = *(const half8*)(ldsBh + l * 32 + qsw);
            half8 fBl = *(const half8*)(ldsBl + l * 32 + qsw);
            #pragma unroll
            for (int i = 0; i < 4; i++) {
                acc[i][j] = __builtin_amdgcn_mfma_f32_16x16x32_f16(fAh[i], fBh, acc[i][j], 0, 0, 0);
                acc[i][j] = __builtin_amdgcn_mfma_f32_16x16x32_f16(fAl[i], fBh, acc[i][j], 0, 0, 0);
                acc[i][j] = __builtin_amdgcn_mfma_f32_16x16x32_f16(fAh[i], fBl, acc[i][j], 0, 0, 0);
            }
        }
        __syncthreads();
    }

    float runmax[4], runsum[4];
    #pragma unroll
    for (int j = 0; j < 4; j++) { runmax[j] = -__builtin_inff(); runsum[j] = 0.f; }
    #pragma unroll
    for (int i = 0; i < 4; i++) {
        #pragma unroll
        for (int r = 0; r < 4; r++) {
            int sg = s0 + ws * 64 + i * 16 + quad * 4 + r;
            if (sg < U) {
                #pragma unroll
                for (int j = 0; j < 4; j++) {
                    runmax[j] = fmaxf(runmax[j], acc[i][j][r]);
                    runsum[j] += acc[i][j][r];
                }
            }
        }
    }
    #pragma unroll
    for (int j = 0; j < 4; j++) {
        int l = wl * 64 + j * 16 + lr;
        redm[ws * 4 + quad][l] = runmax[j];
        reds[ws * 4 + quad][l] = runsum[j];
    }
    __syncthreads();
    if (tid < 128) {
        float gm = -__builtin_inff(), gs = 0.f;
        #pragma unroll
        for (int t = 0; t < 8; t++) { gm = fmaxf(gm, redm[t][tid]); gs += reds[t][tid]; }
        size_t o = ((size_t)b * nst + stile) * CANDMAX + c0 + tid;
        Rmax[o] = gm;
        Rsum[o] = gs;
    }
}

// ---------------------------------------------------------------------------
// Final top-U among refined candidates. grid (B), block 512.
// ---------------------------------------------------------------------------
__global__ __launch_bounds__(512) void topk_final(
    const float* __restrict__ Rmax, const float* __restrict__ Rsum,
    const int* __restrict__ candlist, const int* __restrict__ ncand,
    int* __restrict__ topidx, int U, int nst)
{
    const int b = blockIdx.x;
    const int tid = threadIdx.x;
    __shared__ int wcnt[8];
    __shared__ int basec;
    const int nc = ncand[b];

    unsigned mykey[4];
    #pragma unroll
    for (int t = 0; t < 4; t++) {
        int c = t * 512 + tid;
        float M = -__builtin_inff();
        if (c < nc) {
            float gm = -__builtin_inff(), gs = 0.f;
            for (int st = 0; st < nst; st++) {
                size_t o = ((size_t)b * nst + st) * CANDMAX + c;
                gm = fmaxf(gm, Rmax[o]);
                gs += Rsum[o];
            }
            M = gm - gs * (1.f / (float)L_DIM);
        }
        unsigned bits = __float_as_uint(M);
        mykey[t] = (bits & 0x80000000u) ? ~bits : (bits | 0x80000000u);
    }
    if (tid == 0) basec = 0;

    const int wv = tid >> 6, lane = tid & 63;
    unsigned lo = 0u, hi = 0xFFFFFFFFu;
    while (lo < hi) {
        unsigned hl = hi - lo;
        unsigned mid = lo + (hl >> 1) + (hl & 1u);
        int c = 0;
        #pragma unroll
        for (int t = 0; t < 4; t++) c += (mykey[t] >= mid) ? 1 : 0;
        #pragma unroll
        for (int o = 32; o > 0; o >>= 1) c += __shfl_down(c, o, 64);
        if (lane == 0) wcnt[wv] = c;
        __syncthreads();
        int total = 0;
        #pragma unroll
        for (int i = 0; i < 8; i++) total += wcnt[i];
        if (total >= U) lo = mid; else hi = mid - 1;
        __syncthreads();
    }
    #pragma unroll
    for (int t = 0; t < 4; t++) {
        if (mykey[t] >= lo) {
            int pos = atomicAdd(&basec, 1);
            if (pos < U) topidx[b * U + pos] = candlist[b * CANDMAX + t * 512 + tid];
        }
    }
}

// ---------------------------------------------------------------------------
// v mean from v_h
// ---------------------------------------------------------------------------
__global__ __launch_bounds__(512) void vmean_partial(
    const _Float16* __restrict__ vh, float* __restrict__ partial)
{
    const int ch = blockIdx.x, b = blockIdx.y;
    const int d = threadIdx.x;
    const _Float16* vhb = vh + (size_t)b * ((size_t)D_DIM * L_DIM);
    float acc = 0.f;
    const int lbeg = ch * 128;
    for (int l = lbeg; l < lbeg + 128; l++)
        acc += (float)vhb[(size_t)l * D_DIM + d];
    partial[((size_t)b * 32 + ch) * D_DIM + d] = acc;
}

__global__ __launch_bounds__(512) void vmean_reduce(const float* __restrict__ partial,
                                                    float* __restrict__ vmean)
{
    const int b = blockIdx.x;
    const int d = threadIdx.x;
    float acc = 0.f;
    for (int ch = 0; ch < 32; ch++) acc += partial[((size_t)b * 32 + ch) * D_DIM + d];
    vmean[b * D_DIM + d] = acc * (1.f / (float)L_DIM);
}

__global__ __launch_bounds__(256) void fill_out(const float* __restrict__ vmean,
                                                float* __restrict__ out)
{
    const int z = blockIdx.x;
    const int b = z >> 6, lch = z & 63;
    __shared__ float vm[512];
    vm[threadIdx.x] = vmean[b * 512 + threadIdx.x];
    vm[threadIdx.x + 256] = vmean[b * 512 + threadIdx.x + 256];
    __syncthreads();
    float* op = out + (size_t)b * ((size_t)D_DIM * L_DIM) + (size_t)lch * 64 * 512;
    #pragma unroll
    for (int it = 0; it < 32; it++) {
        int flat = (threadIdx.x + it * 256) * 4;
        int d = flat & 511;
        float4 r = { vm[d], vm[d + 1], vm[d + 2], vm[d + 3] };
        *(float4*)&op[flat] = r;
    }
}

// Zero selected output rows ahead of atomic accumulation. grid (U, B), block 256
__global__ __launch_bounds__(256) void zero_sel(const int* __restrict__ topidx,
                                                float* __restrict__ out, int U)
{
    const int u = blockIdx.x, b = blockIdx.y;
    int row = topidx[b * U + u];
    float2 z = { 0.f, 0.f };
    *(float2*)&out[(size_t)b * ((size_t)D_DIM * L_DIM) + (size_t)row * 512
                   + threadIdx.x * 2] = z;
}

// ---------------------------------------------------------------------------
// scores via SINGLE fp16 MFMA. grid: (32 s-tiles, u-tiles, 16 b), block 256
// ---------------------------------------------------------------------------
__global__ __launch_bounds__(256) void scores_mfma(
    const _Float16* __restrict__ qh, const _Float16* __restrict__ kh,
    const int* __restrict__ topidx,
    _Float16* __restrict__ sh, int U)
{
    const int b = blockIdx.z;
    const int s0 = blockIdx.x * 128;
    const int u0 = blockIdx.y * 128;
    const size_t perB = (size_t)D_DIM * L_DIM;
    const _Float16* qh_b = qh + (size_t)b * perB;
    const _Float16* kh_b = kh + (size_t)b * perB;
    _Float16* sh_b = sh + (size_t)b * (size_t)U * L_DIM;

    __shared__ _Float16 ldsAh[4096];
    __shared__ _Float16 ldsBh[4096];
    __shared__ int arow[128];

    const int tid = threadIdx.x;
    const int w4 = tid >> 6, lane = tid & 63;
    const int lr = lane & 15, quad = lane >> 4;
    const int wu = w4 >> 1, wn = w4 & 1;

    if (tid < 128) {
        int u = u0 + tid;
        arow[tid] = topidx[b * U + (u < U ? u : U - 1)];
    }
    __syncthreads();

    f32x4 acc[4][4] = {};
    const int qsw = (quad ^ ((lr >> 1) & 3)) * 8;

    for (int k0 = 0; k0 < 512; k0 += 32) {
        #pragma unroll
        for (int t = 0; t < 2; t++) {
            int c = w4 * 128 + t * 64 + lane;
            int row = c >> 2, part = (c & 3) ^ ((row >> 1) & 3);
            size_t go = (size_t)arow[row] * 512 + k0 + part * 8;
            size_t ko = (size_t)(s0 + row) * 512 + k0 + part * 8;
            int base = (w4 * 128 + t * 64) * 8;
            gld16(qh_b + go, ldsAh + base);
            gld16(kh_b + ko, ldsBh + base);
        }
        __syncthreads();

        half8 fAh[4];
        #pragma unroll
        for (int i = 0; i < 4; i++) {
            int u = wu * 64 + i * 16 + lr;
            fAh[i] = *(const half8*)(ldsAh + u * 32 + qsw);
        }
        #pragma unroll
        for (int j = 0; j < 4; j++) {
            int s = wn * 64 + j * 16 + lr;
            half8 fBh = *(const half8*)(ldsBh + s * 32 + qsw);
            #pragma unroll
            for (int i = 0; i < 4; i++)
                acc[i][j] = __builtin_amdgcn_mfma_f32_16x16x32_f16(fAh[i], fBh, acc[i][j], 0, 0, 0);
        }
        __syncthreads();
    }

    const float scale = 0.044194173824159216f;   // 1/sqrt(512)
    #pragma unroll
    for (int i = 0; i < 4; i++) {
        #pragma unroll
        for (int r = 0; r < 4; r++) {
            int u = u0 + wu * 64 + i * 16 + quad * 4 + r;
            if (u < U) {
                #pragma unroll
                for (int j = 0; j < 4; j++) {
                    int s = s0 + wn * 64 + j * 16 + lr;
                    sh_b[(size_t)u * L_DIM + s] = (_Float16)(acc[i][j][r] * scale);
                }
            }
        }
    }
}

// ---------------------------------------------------------------------------
// Row softmax over 4096, fp16 in/out (in place). grid (B*U), block 256
// ---------------------------------------------------------------------------
__global__ __launch_bounds__(256) void softmax_h(_Float16* __restrict__ sh)
{
    _Float16* hrow = sh + (size_t)blockIdx.x * L_DIM;
    const int tid = threadIdx.x;
    float x[16];
    #pragma unroll
    for (int t = 0; t < 2; t++) {
        half8 h8 = *(const half8*)(hrow + tid * 8 + t * 2048);
        #pragma unroll
        for (int i = 0; i < 8; i++) x[t * 8 + i] = (float)h8[i];
    }
    __shared__ float red[256];
    float lm = -__builtin_inff();
    #pragma unroll
    for (int i = 0; i < 16; i++) lm = fmaxf(lm, x[i]);
    red[tid] = lm;
    __syncthreads();
    for (int o = 128; o > 0; o >>= 1) {
        if (tid < o) red[tid] = fmaxf(red[tid], red[tid + o]);
        __syncthreads();
    }
    float m = red[0];
    __syncthreads();
    float ls = 0.f;
    #pragma unroll
    for (int i = 0; i < 16; i++) { x[i] = __expf(x[i] - m); ls += x[i]; }
    red[tid] = ls;
    __syncthreads();
    for (int o = 128; o > 0; o >>= 1) {
        if (tid < o) red[tid] += red[tid + o];
        __syncthreads();
    }
    float inv = 1.f / red[0];
    #pragma unroll
    for (int t = 0; t < 2; t++) {
        half8 h8;
        #pragma unroll
        for (int i = 0; i < 8; i++) h8[i] = (_Float16)(x[t * 8 + i] * inv);
        *(half8*)(hrow + tid * 8 + t * 2048) = h8;
    }
}

// ---------------------------------------------------------------------------
// upd via SINGLE fp16 MFMA, K-split x4, atomic accumulate into zeroed rows.
// grid: ((U+127)/128 u-tiles, 4 dd-tiles, 16*KSPLIT), block 256
// ---------------------------------------------------------------------------
__global__ __launch_bounds__(256) void upd_mfma(
    const _Float16* __restrict__ sh, const _Float16* __restrict__ vh,
    const int* __restrict__ topidx, float* __restrict__ out, int U)
{
    const int zz = blockIdx.z;
    const int b = zz >> 2, ks = zz & 3;
    const int n0 = blockIdx.y * 128;
    const int u0 = blockIdx.x * 128;
    const size_t perB = (size_t)D_DIM * L_DIM;
    const _Float16* ah_b = sh + (size_t)b * (size_t)U * L_DIM;
    const _Float16* vh_b = vh + (size_t)b * perB;

    __shared__ _Float16 ldsAh[4096];
    __shared__ _Float16 ldsBh[4096];

    const int tid = threadIdx.x;
    const int w4 = tid >> 6, lane = tid & 63;
    const int lr = lane & 15, quad = lane >> 4;
    const int wu = w4 >> 1, wd = w4 & 1;

    const int part = tid & 15, spair = tid >> 4;
    const int s_b = spair * 2;
    const int colw = ((spair >> 2) + part) & 3;
    const int so2 = (s_b & 7);

    f32x4 acc[4][4] = {};
    const int qsw = (quad ^ ((lr >> 1) & 3)) * 8;

    const int kbeg = ks * (L_DIM / KSPLIT);
    const int kend = kbeg + (L_DIM / KSPLIT);
    for (int k0 = kbeg; k0 < kend; k0 += 32) {
        #pragma unroll
        for (int t = 0; t < 2; t++) {
            int c = w4 * 128 + t * 64 + lane;
            int u = c >> 2, pt = (c & 3) ^ ((u >> 1) & 3);
            int urow = u0 + u; if (urow >= U) urow = U - 1;
            size_t ao = (size_t)urow * L_DIM + k0 + pt * 8;
            int base = (w4 * 128 + t * 64) * 8;
            gld16(ah_b + ao, ldsAh + base);
        }
        {
            const _Float16* s0p = vh_b + (size_t)(k0 + s_b) * 512 + n0 + part * 8;
            const _Float16* s1p = s0p + 512;
            ushort8 a0 = *(const ushort8*)s0p;
            ushort8 a1 = *(const ushort8*)s1p;
            #pragma unroll
            for (int t = 0; t < 8; t++) {
                int dd = part * 8 + t;
                unsigned int ph = (unsigned int)a0[t] | ((unsigned int)a1[t] << 16);
                *(unsigned int*)(ldsBh + dd * 32 + colw * 8 + so2) = ph;
            }
        }
        __syncthreads();

        half8 fAh[4];
        #pragma unroll
        for (int i = 0; i < 4; i++) {
            int u = wu * 64 + i * 16 + lr;
            fAh[i] = *(const half8*)(ldsAh + u * 32 + qsw);
        }
        #pragma unroll
        for (int j = 0; j < 4; j++) {
            int dd = wd * 64 + j * 16 + lr;
            int col = (quad + (dd >> 3)) & 3;
            half8 fBh = *(const half8*)(ldsBh + dd * 32 + col * 8);
            #pragma unroll
            for (int i = 0; i < 4; i++)
                acc[i][j] = __builtin_amdgcn_mfma_f32_16x16x32_f16(fAh[i], fBh, acc[i][j], 0, 0, 0);
        }
        __syncthreads();
    }

    #pragma unroll
    for (int i = 0; i < 4; i++) {
        #pragma unroll
        for (int r = 0; r < 4; r++) {
            int u = u0 + wu * 64 + i * 16 + quad * 4 + r;
            if (u < U) {
                int lrow = topidx[b * U + u];
                #pragma unroll
                for (int j = 0; j < 4; j++) {
                    int dd = n0 + wd * 64 + j * 16 + lr;
                    unsafeAtomicAdd(&out[(size_t)b * perB + (size_t)lrow * 512 + dd],
                                    acc[i][j][r]);
                }
            }
        }
    }
}

// ---------------------------------------------------------------------------
extern "C" void kernel_launch(void* const* d_in, const int* in_sizes, int n_in,
                              void* d_out, int out_size, void* d_ws, size_t ws_size,
                              hipStream_t stream)
{
    const float* x1 = (const float*)d_in[0];
    const float* x2 = (const float*)d_in[1];
    const float* Wq = (const float*)d_in[2];
    const float* bq = (const float*)d_in[3];
    const float* Wk = (const float*)d_in[4];
    const float* bk = (const float*)d_in[5];
    const float* Wv = (const float*)d_in[6];
    const float* bv = (const float*)d_in[7];
    const int*  idx = (const int*)d_in[8];
    const int U = in_sizes[8];            // 450
    const int nst = (U + 127) / 128;      // 4

    float* out = (float*)d_out;

    const size_t perB = (size_t)D_DIM * L_DIM;          // 2,097,152
    const size_t tenH = (size_t)BATCH * perB;           // 33,554,432 halves
    _Float16* qh = (_Float16*)d_ws;
    _Float16* ql = qh + tenH;
    _Float16* kh = ql + tenH;
    _Float16* kl = kh + tenH;
    _Float16* vh = kl + tenH;
    float* S = (float*)(vh + tenH);                     // union region (~202 MB)

    // proj-phase aliases inside S:
    _Float16* XTh = (_Float16*)S;
    _Float16* XTl = XTh + (size_t)8 * L_DIM * 512;
    _Float16* Wh  = XTl + (size_t)8 * L_DIM * 512;
    _Float16* Wl  = Wh + (size_t)3 * 512 * 512;

    // post-proj aliases inside S:
    _Float16* sh = (_Float16*)S;
    float* vmean = (float*)(sh + (size_t)BATCH * (size_t)U * L_DIM);
    float* partU = vmean + (size_t)BATCH * D_DIM;
    float* vpart = partU;                               // vmean partials (1 MB)
    float* Mmax  = partU;                               // then qks partials (2 MB)
    float* Msum  = Mmax + (size_t)BATCH * nst * L_DIM;
    int* topidx   = (int*)(Msum + (size_t)BATCH * nst * L_DIM);
    int* candlist = topidx + BATCH * 512;
    int* ncand    = candlist + BATCH * CANDMAX;
    float* Rmax   = (float*)(ncand + 64);
    float* Rsum   = Rmax + (size_t)BATCH * nst * CANDMAX;

    // 1. split W
    convert_w<<<dim3(1024, 3), 256, 0, stream>>>(Wq, Wk, Wv, Wh, Wl);

    // 2. projections (two 8-batch phases): q/k K-stacked x3 pipelined, v x1
    for (int phase = 0; phase < 2; phase++) {
        convert_x<<<dim3(64, 8, 8), 256, 0, stream>>>(x1, x2, XTh, XTl, phase);
        proj_qk_pipe<<<dim3(L_DIM / 256, D_DIM / 256, 8 * 2), 512, 0, stream>>>(
            Wh, Wl, XTh, XTl, bq, bk, qh, ql, kh, kl, phase);
        proj_mfma_v<<<dim3(L_DIM / 128, D_DIM / 128, 8), 256, 0, stream>>>(
            Wh, XTh, bv, vh, phase);
    }

    // 3. v mean + output fill
    vmean_partial<<<dim3(32, BATCH), 512, 0, stream>>>(vh, vpart);
    vmean_reduce<<<BATCH, 512, 0, stream>>>(vpart, vmean);
    fill_out<<<BATCH * 64, 256, 0, stream>>>(vmean, out);

    // 4. sampled QK^T: x1 bulk -> candidate select -> x3 refine -> final top-U
    qks_x1<<<dim3(L_DIM / 128, nst, BATCH), 256, 0, stream>>>(
        qh, kh, idx, Mmax, Msum, U, nst);
    topk_cand<<<BATCH, 512, 0, stream>>>(Mmax, Msum, candlist, ncand, U, nst);
    refine_mfma<<<dim3(CANDMAX / 128, nst, BATCH), 256, 0, stream>>>(
        qh, ql, kh, kl, idx, candlist, ncand, Rmax, Rsum, U, nst);
    topk_final<<<BATCH, 512, 0, stream>>>(Rmax, Rsum, candlist, ncand, topidx, U, nst);

    // 5. scores (fp16), softmax, zero selected rows, attn @ V atomic scatter
    const int utiles = (U + 127) / 128;
    scores_mfma<<<dim3(L_DIM / 128, utiles, BATCH), 256, 0, stream>>>(
        qh, kh, topidx, sh, U);
    softmax_h<<<BATCH * U, 256, 0, stream>>>(sh);
    zero_sel<<<dim3(U, BATCH), 256, 0, stream>>>(topidx, out, U);
    upd_mfma<<<dim3(utiles, D_DIM / 128, BATCH * KSPLIT), 256, 0, stream>>>(
        sh, vh, topidx, out, U);
}

// Round 6
// 880.599 us; speedup vs baseline: 1.0549x; 1.0549x over previous
//
#include <hip/hip_runtime.h>
#include <cstdint>
#include <cstddef>

#define L_DIM 4096
#define D_DIM 512
#define CIN   256
#define BATCH 16
#define KSPLIT 4

typedef _Float16 half8 __attribute__((ext_vector_type(8)));
typedef unsigned short ushort8 __attribute__((ext_vector_type(8)));
typedef float f32x4 __attribute__((ext_vector_type(4)));

__device__ __forceinline__ void gld16(const _Float16* g, _Float16* l) {
    __builtin_amdgcn_global_load_lds(
        (const __attribute__((address_space(1))) unsigned int*)g,
        (__attribute__((address_space(3))) unsigned int*)l,
        16, 0, 0);
}

// ---------------------------------------------------------------------------
// Split W (3 x 512x512 fp32) into fp16 hi/lo. grid (1024,3), block 256
// ---------------------------------------------------------------------------
__global__ __launch_bounds__(256) void convert_w(
    const float* __restrict__ Wq, const float* __restrict__ Wk,
    const float* __restrict__ Wv,
    _Float16* __restrict__ Wh, _Float16* __restrict__ Wl)
{
    const int w = blockIdx.y;
    const float* src = (w == 0) ? Wq : (w == 1) ? Wk : Wv;
    int i = blockIdx.x * 256 + threadIdx.x;
    float xv = src[i];
    _Float16 hi = (_Float16)xv;
    Wh[(size_t)w * 262144 + i] = hi;
    Wl[(size_t)w * 262144 + i] = (_Float16)(xv - (float)hi);
}

// ---------------------------------------------------------------------------
// Transpose + split X. Per phase 8 batches. grid (64, 8, 8), block 256.
// ---------------------------------------------------------------------------
__global__ __launch_bounds__(256) void convert_x(
    const float* __restrict__ x1, const float* __restrict__ x2,
    _Float16* __restrict__ XTh, _Float16* __restrict__ XTl, int phase)
{
    const int bb = blockIdx.z;
    const int b = phase * 8 + bb;
    const int s0 = blockIdx.x * 64;
    const int c0 = blockIdx.y * 64;
    __shared__ float t[64][65];
    const int tid = threadIdx.x;
    const int g = tid >> 6, sy = tid & 63;
    const float* src = (c0 < CIN)
        ? (x1 + (size_t)b * CIN * L_DIM + (size_t)c0 * L_DIM)
        : (x2 + (size_t)b * CIN * L_DIM + (size_t)(c0 - CIN) * L_DIM);
    #pragma unroll
    for (int r = 0; r < 16; r++) {
        int cl = g * 16 + r;
        t[cl][sy] = src[(size_t)cl * L_DIM + s0 + sy];
    }
    __syncthreads();
    _Float16* outh = XTh + (size_t)bb * L_DIM * 512 + (size_t)s0 * 512 + c0;
    _Float16* outl = XTl + (size_t)bb * L_DIM * 512 + (size_t)s0 * 512 + c0;
    #pragma unroll
    for (int r = 0; r < 16; r++) {
        int sl = g * 16 + r;
        float xv = t[sy][sl];
        _Float16 hi = (_Float16)xv;
        float lo = xv - (float)hi;
        outh[(size_t)sl * 512 + sy] = hi;
        outl[(size_t)sl * 512 + sy] = (_Float16)lo;
    }
}

// ---------------------------------------------------------------------------
// q/k projection via fp16x3 MFMA, hi+lo outputs, swizzled LDS.
// grid: (32, 4, 16), block 256
// ---------------------------------------------------------------------------
__global__ __launch_bounds__(256) void proj_mfma_qk(
    const _Float16* __restrict__ Wh, const _Float16* __restrict__ Wl,
    const _Float16* __restrict__ XTh, const _Float16* __restrict__ XTl,
    const float* __restrict__ bq, const float* __restrict__ bk,
    _Float16* __restrict__ qh, _Float16* __restrict__ ql,
    _Float16* __restrict__ kh, _Float16* __restrict__ kl,
    int phase)
{
    const int z = blockIdx.z;
    const int bb = z >> 1, w = z & 1;
    const int b = phase * 8 + bb;
    const _Float16* Ah_g = Wh + (size_t)w * 262144;
    const _Float16* Al_g = Wl + (size_t)w * 262144;
    const _Float16* Bh_g = XTh + (size_t)bb * ((size_t)L_DIM * 512);
    const _Float16* Bl_g = XTl + (size_t)bb * ((size_t)L_DIM * 512);
    const float* bias = (w == 0) ? bq : bk;
    _Float16* outh = ((w == 0) ? qh : kh) + (size_t)b * ((size_t)D_DIM * L_DIM);
    _Float16* outl = ((w == 0) ? ql : kl) + (size_t)b * ((size_t)D_DIM * L_DIM);

    const int m0 = blockIdx.y * 128;
    const int n0 = blockIdx.x * 128;

    __shared__ _Float16 lds[4 * 128 * 32];
    _Float16* ldsA_h = lds;
    _Float16* ldsA_l = lds + 4096;
    _Float16* ldsB_h = lds + 8192;
    _Float16* ldsB_l = lds + 12288;

    const int tid = threadIdx.x;
    const int w4 = tid >> 6, lane = tid & 63;
    const int lr = lane & 15, quad = lane >> 4;
    const int wr = w4 >> 1, wc = w4 & 1;

    f32x4 acc[4][4] = {};

    const int q1 = w4 * 128 + lane, q2 = q1 + 64;
    const int r1 = q1 >> 2, c41 = (q1 & 3) ^ ((r1 >> 1) & 3);
    const int r2 = q2 >> 2, c42 = (q2 & 3) ^ ((r2 >> 1) & 3);

    const _Float16* pAh1 = Ah_g + (size_t)(m0 + r1) * 512 + c41 * 8;
    const _Float16* pAh2 = Ah_g + (size_t)(m0 + r2) * 512 + c42 * 8;
    const _Float16* pAl1 = Al_g + (size_t)(m0 + r1) * 512 + c41 * 8;
    const _Float16* pAl2 = Al_g + (size_t)(m0 + r2) * 512 + c42 * 8;
    const _Float16* pBh1 = Bh_g + (size_t)(n0 + r1) * 512 + c41 * 8;
    const _Float16* pBh2 = Bh_g + (size_t)(n0 + r2) * 512 + c42 * 8;
    const _Float16* pBl1 = Bl_g + (size_t)(n0 + r1) * 512 + c41 * 8;
    const _Float16* pBl2 = Bl_g + (size_t)(n0 + r2) * 512 + c42 * 8;

    _Float16* d1 = (_Float16*)(lds) + (size_t)(w4 * 128) * 8;
    _Float16* d2 = (_Float16*)(lds) + (size_t)(w4 * 128 + 64) * 8;

    const int qsw = (quad ^ ((lr >> 1) & 3)) * 8;

    for (int k0 = 0; k0 < 512; k0 += 32) {
        if (k0) __syncthreads();
        gld16(pAh1 + k0, d1);
        gld16(pAh2 + k0, d2);
        gld16(pAl1 + k0, d1 + 4096);
        gld16(pAl2 + k0, d2 + 4096);
        gld16(pBh1 + k0, d1 + 8192);
        gld16(pBh2 + k0, d2 + 8192);
        gld16(pBl1 + k0, d1 + 12288);
        gld16(pBl2 + k0, d2 + 12288);
        __syncthreads();

        half8 fAh[4], fAl[4];
        #pragma unroll
        for (int i = 0; i < 4; i++) {
            int m = wr * 64 + i * 16 + lr;
            fAh[i] = *(const half8*)(ldsA_h + m * 32 + qsw);
            fAl[i] = *(const half8*)(ldsA_l + m * 32 + qsw);
        }
        #pragma unroll
        for (int j = 0; j < 4; j++) {
            int n = wc * 64 + j * 16 + lr;
            half8 fBh = *(const half8*)(ldsB_h + n * 32 + qsw);
            half8 fBl = *(const half8*)(ldsB_l + n * 32 + qsw);
            #pragma unroll
            for (int i = 0; i < 4; i++) {
                acc[i][j] = __builtin_amdgcn_mfma_f32_16x16x32_f16(fAh[i], fBh, acc[i][j], 0, 0, 0);
                acc[i][j] = __builtin_amdgcn_mfma_f32_16x16x32_f16(fAl[i], fBh, acc[i][j], 0, 0, 0);
                acc[i][j] = __builtin_amdgcn_mfma_f32_16x16x32_f16(fAh[i], fBl, acc[i][j], 0, 0, 0);
            }
        }
    }

    #pragma unroll
    for (int i = 0; i < 4; i++) {
        int mg = m0 + wr * 64 + i * 16 + quad * 4;
        #pragma unroll
        for (int r = 0; r < 4; r++) {
            float bvv = bias[mg + r];
            #pragma unroll
            for (int j = 0; j < 4; j++) {
                int ng = n0 + wc * 64 + j * 16 + lr;
                float val = acc[i][j][r] + bvv;
                _Float16 hi = (_Float16)val;
                size_t off = (size_t)(mg + r) * L_DIM + ng;
                outh[off] = hi;
                outl[off] = (_Float16)(val - (float)hi);
            }
        }
    }
}

// ---------------------------------------------------------------------------
// V projection: hi-only single-MFMA GEMM. grid: (32, 4, 8), block 256
// ---------------------------------------------------------------------------
__global__ __launch_bounds__(256) void proj_mfma_v(
    const _Float16* __restrict__ Wh, const _Float16* __restrict__ XTh,
    const float* __restrict__ bv, _Float16* __restrict__ vh, int phase)
{
    const int bb = blockIdx.z;
    const int b = phase * 8 + bb;
    const _Float16* Ah_g = Wh + (size_t)2 * 262144;
    const _Float16* Bh_g = XTh + (size_t)bb * ((size_t)L_DIM * 512);
    _Float16* outh = vh + (size_t)b * ((size_t)D_DIM * L_DIM);

    const int m0 = blockIdx.y * 128;
    const int n0 = blockIdx.x * 128;

    __shared__ _Float16 lds[2 * 128 * 32];
    _Float16* ldsA_h = lds;
    _Float16* ldsB_h = lds + 4096;

    const int tid = threadIdx.x;
    const int w4 = tid >> 6, lane = tid & 63;
    const int lr = lane & 15, quad = lane >> 4;
    const int wr = w4 >> 1, wc = w4 & 1;

    f32x4 acc[4][4] = {};

    const int q1 = w4 * 128 + lane, q2 = q1 + 64;
    const int r1 = q1 >> 2, c41 = (q1 & 3) ^ ((r1 >> 1) & 3);
    const int r2 = q2 >> 2, c42 = (q2 & 3) ^ ((r2 >> 1) & 3);

    const _Float16* pAh1 = Ah_g + (size_t)(m0 + r1) * 512 + c41 * 8;
    const _Float16* pAh2 = Ah_g + (size_t)(m0 + r2) * 512 + c42 * 8;
    const _Float16* pBh1 = Bh_g + (size_t)(n0 + r1) * 512 + c41 * 8;
    const _Float16* pBh2 = Bh_g + (size_t)(n0 + r2) * 512 + c42 * 8;

    _Float16* d1 = (_Float16*)(lds) + (size_t)(w4 * 128) * 8;
    _Float16* d2 = (_Float16*)(lds) + (size_t)(w4 * 128 + 64) * 8;

    const int qsw = (quad ^ ((lr >> 1) & 3)) * 8;

    for (int k0 = 0; k0 < 512; k0 += 32) {
        if (k0) __syncthreads();
        gld16(pAh1 + k0, d1);
        gld16(pAh2 + k0, d2);
        gld16(pBh1 + k0, d1 + 4096);
        gld16(pBh2 + k0, d2 + 4096);
        __syncthreads();

        half8 fAh[4];
        #pragma unroll
        for (int i = 0; i < 4; i++) {
            int m = wr * 64 + i * 16 + lr;
            fAh[i] = *(const half8*)(ldsA_h + m * 32 + qsw);
        }
        #pragma unroll
        for (int j = 0; j < 4; j++) {
            int n = wc * 64 + j * 16 + lr;
            half8 fBh = *(const half8*)(ldsB_h + n * 32 + qsw);
            #pragma unroll
            for (int i = 0; i < 4; i++)
                acc[i][j] = __builtin_amdgcn_mfma_f32_16x16x32_f16(fAh[i], fBh, acc[i][j], 0, 0, 0);
        }
    }

    #pragma unroll
    for (int i = 0; i < 4; i++) {
        int mg = m0 + wr * 64 + i * 16 + quad * 4;
        #pragma unroll
        for (int r = 0; r < 4; r++) {
            float bvv = bv[mg + r];
            #pragma unroll
            for (int j = 0; j < 4; j++) {
                int ng = n0 + wc * 64 + j * 16 + lr;
                outh[(size_t)(mg + r) * L_DIM + ng] = (_Float16)(acc[i][j][r] + bvv);
            }
        }
    }
}

// ---------------------------------------------------------------------------
// qks via fp16x3 MFMA, one s-tile per block, partial max/sum out.
// grid: (32 l-tiles, nst s-tiles, 16 b), block 256
// ---------------------------------------------------------------------------
__global__ __launch_bounds__(256) void qks_mfma(
    const _Float16* __restrict__ qh, const _Float16* __restrict__ ql,
    const _Float16* __restrict__ kh, const _Float16* __restrict__ kl,
    const int* __restrict__ idx_sample,
    float* __restrict__ Mmax, float* __restrict__ Msum, int U, int nst)
{
    const int b = blockIdx.z;
    const int stile = blockIdx.y;
    const int l0 = blockIdx.x * 128;
    const int s0 = stile * 128;
    const size_t perB = (size_t)D_DIM * L_DIM;
    const _Float16* qh_b = qh + (size_t)b * perB;
    const _Float16* ql_b = ql + (size_t)b * perB;
    const _Float16* kh_b = kh + (size_t)b * perB;
    const _Float16* kl_b = kl + (size_t)b * perB;

    __shared__ _Float16 ldsAh[4096], ldsAl[4096];   // gathered k [s][32]
    __shared__ _Float16 ldsBh[4096], ldsBl[4096];   // q [l][32]
    __shared__ int sidx[128];
    __shared__ float redm[8][128];
    __shared__ float reds[8][128];

    const int tid = threadIdx.x;
    const int w4 = tid >> 6, lane = tid & 63;
    const int lr = lane & 15, quad = lane >> 4;
    const int ws = w4 >> 1, wl = w4 & 1;

    if (tid < 128) {
        int s = s0 + tid;
        sidx[tid] = (s < U) ? idx_sample[s] : idx_sample[0];
    }
    __syncthreads();

    f32x4 acc[4][4] = {};
    const int qsw = (quad ^ ((lr >> 1) & 3)) * 8;

    for (int k0 = 0; k0 < 512; k0 += 32) {
        #pragma unroll
        for (int t = 0; t < 2; t++) {
            int c = w4 * 128 + t * 64 + lane;
            int row = c >> 2, part = (c & 3) ^ ((row >> 1) & 3);
            int krow = sidx[row];
            size_t go = (size_t)krow * 512 + k0 + part * 8;
            size_t qo = (size_t)(l0 + row) * 512 + k0 + part * 8;
            int base = (w4 * 128 + t * 64) * 8;
            gld16(kh_b + go, ldsAh + base);
            gld16(kl_b + go, ldsAl + base);
            gld16(qh_b + qo, ldsBh + base);
            gld16(ql_b + qo, ldsBl + base);
        }
        __syncthreads();

        half8 fAh[4], fAl[4];
        #pragma unroll
        for (int i = 0; i < 4; i++) {
            int s = ws * 64 + i * 16 + lr;
            fAh[i] = *(const half8*)(ldsAh + s * 32 + qsw);
            fAl[i] = *(const half8*)(ldsAl + s * 32 + qsw);
        }
        #pragma unroll
        for (int j = 0; j < 4; j++) {
            int l = wl * 64 + j * 16 + lr;
            half8 fBh = *(const half8*)(ldsBh + l * 32 + qsw);
            half8 fBl = *(const half8*)(ldsBl + l * 32 + qsw);
            #pragma unroll
            for (int i = 0; i < 4; i++) {
                acc[i][j] = __builtin_amdgcn_mfma_f32_16x16x32_f16(fAh[i], fBh, acc[i][j], 0, 0, 0);
                acc[i][j] = __builtin_amdgcn_mfma_f32_16x16x32_f16(fAl[i], fBh, acc[i][j], 0, 0, 0);
                acc[i][j] = __builtin_amdgcn_mfma_f32_16x16x32_f16(fAh[i], fBl, acc[i][j], 0, 0, 0);
            }
        }
        __syncthreads();
    }

    float runmax[4], runsum[4];
    #pragma unroll
    for (int j = 0; j < 4; j++) { runmax[j] = -__builtin_inff(); runsum[j] = 0.f; }
    #pragma unroll
    for (int i = 0; i < 4; i++) {
        #pragma unroll
        for (int r = 0; r < 4; r++) {
            int sg = s0 + ws * 64 + i * 16 + quad * 4 + r;
            if (sg < U) {
                #pragma unroll
                for (int j = 0; j < 4; j++) {
                    runmax[j] = fmaxf(runmax[j], acc[i][j][r]);
                    runsum[j] += acc[i][j][r];
                }
            }
        }
    }
    #pragma unroll
    for (int j = 0; j < 4; j++) {
        int l = wl * 64 + j * 16 + lr;
        redm[ws * 4 + quad][l] = runmax[j];
        reds[ws * 4 + quad][l] = runsum[j];
    }
    __syncthreads();
    if (tid < 128) {
        float gm = -__builtin_inff(), gs = 0.f;
        #pragma unroll
        for (int t = 0; t < 8; t++) { gm = fmaxf(gm, redm[t][tid]); gs += reds[t][tid]; }
        size_t o = ((size_t)b * nst + stile) * L_DIM + l0 + tid;
        Mmax[o] = gm;
        Msum[o] = gs;
    }
}

// ---------------------------------------------------------------------------
// Per-batch top-U: reduce partials -> M, binary-search threshold on key bits,
// compact indices (set semantics). grid (B), block 512.
// ---------------------------------------------------------------------------
__global__ __launch_bounds__(512) void topk_select(
    const float* __restrict__ Mmax, const float* __restrict__ Msum,
    int* __restrict__ topidx, int U, int nst)
{
    const int b = blockIdx.x;
    const int tid = threadIdx.x;
    __shared__ int wcnt[8];
    __shared__ int basec;

    unsigned mykey[8];
    #pragma unroll
    for (int t = 0; t < 8; t++) {
        int l = t * 512 + tid;
        float gm = -__builtin_inff(), gs = 0.f;
        for (int st = 0; st < nst; st++) {
            size_t o = ((size_t)b * nst + st) * L_DIM + l;
            gm = fmaxf(gm, Mmax[o]);
            gs += Msum[o];
        }
        float M = gm - gs * (1.f / (float)L_DIM);
        unsigned bits = __float_as_uint(M);
        mykey[t] = (bits & 0x80000000u) ? ~bits : (bits | 0x80000000u);
    }
    if (tid == 0) basec = 0;

    const int wv = tid >> 6, lane = tid & 63;
    unsigned lo = 0u, hi = 0xFFFFFFFFu;
    while (lo < hi) {
        unsigned hl = hi - lo;
        unsigned mid = lo + (hl >> 1) + (hl & 1u);   // ceil midpoint, overflow-safe
        int c = 0;
        #pragma unroll
        for (int t = 0; t < 8; t++) c += (mykey[t] >= mid) ? 1 : 0;
        #pragma unroll
        for (int o = 32; o > 0; o >>= 1) c += __shfl_down(c, o, 64);
        if (lane == 0) wcnt[wv] = c;
        __syncthreads();
        int total = 0;
        #pragma unroll
        for (int i = 0; i < 8; i++) total += wcnt[i];
        if (total >= U) lo = mid; else hi = mid - 1;
        __syncthreads();
    }
    #pragma unroll
    for (int t = 0; t < 8; t++) {
        if (mykey[t] >= lo) {
            int pos = atomicAdd(&basec, 1);
            if (pos < U) topidx[b * U + pos] = t * 512 + tid;
        }
    }
}

// ---------------------------------------------------------------------------
// v mean from v_h
// ---------------------------------------------------------------------------
__global__ __launch_bounds__(512) void vmean_partial(
    const _Float16* __restrict__ vh, float* __restrict__ partial)
{
    const int ch = blockIdx.x, b = blockIdx.y;
    const int d = threadIdx.x;
    const _Float16* vhb = vh + (size_t)b * ((size_t)D_DIM * L_DIM);
    float acc = 0.f;
    const int lbeg = ch * 128;
    for (int l = lbeg; l < lbeg + 128; l++)
        acc += (float)vhb[(size_t)l * D_DIM + d];
    partial[((size_t)b * 32 + ch) * D_DIM + d] = acc;
}

__global__ __launch_bounds__(512) void vmean_reduce(const float* __restrict__ partial,
                                                    float* __restrict__ vmean)
{
    const int b = blockIdx.x;
    const int d = threadIdx.x;
    float acc = 0.f;
    for (int ch = 0; ch < 32; ch++) acc += partial[((size_t)b * 32 + ch) * D_DIM + d];
    vmean[b * D_DIM + d] = acc * (1.f / (float)L_DIM);
}

__global__ __launch_bounds__(256) void fill_out(const float* __restrict__ vmean,
                                                float* __restrict__ out)
{
    const int z = blockIdx.x;
    const int b = z >> 6, lch = z & 63;
    __shared__ float vm[512];
    vm[threadIdx.x] = vmean[b * 512 + threadIdx.x];
    vm[threadIdx.x + 256] = vmean[b * 512 + threadIdx.x + 256];
    __syncthreads();
    float* op = out + (size_t)b * ((size_t)D_DIM * L_DIM) + (size_t)lch * 64 * 512;
    #pragma unroll
    for (int it = 0; it < 32; it++) {
        int flat = (threadIdx.x + it * 256) * 4;
        int d = flat & 511;
        float4 r = { vm[d], vm[d + 1], vm[d + 2], vm[d + 3] };
        *(float4*)&op[flat] = r;
    }
}

// Zero selected output rows ahead of atomic accumulation. grid (U, B), block 256
__global__ __launch_bounds__(256) void zero_sel(const int* __restrict__ topidx,
                                                float* __restrict__ out, int U)
{
    const int u = blockIdx.x, b = blockIdx.y;
    int row = topidx[b * U + u];
    float2 z = { 0.f, 0.f };
    *(float2*)&out[(size_t)b * ((size_t)D_DIM * L_DIM) + (size_t)row * 512
                   + threadIdx.x * 2] = z;
}

// ---------------------------------------------------------------------------
// scores via SINGLE fp16 MFMA. grid: (32 s-tiles, u-tiles, 16 b), block 256
// ---------------------------------------------------------------------------
__global__ __launch_bounds__(256) void scores_mfma(
    const _Float16* __restrict__ qh, const _Float16* __restrict__ kh,
    const int* __restrict__ topidx,
    _Float16* __restrict__ sh, int U)
{
    const int b = blockIdx.z;
    const int s0 = blockIdx.x * 128;
    const int u0 = blockIdx.y * 128;
    const size_t perB = (size_t)D_DIM * L_DIM;
    const _Float16* qh_b = qh + (size_t)b * perB;
    const _Float16* kh_b = kh + (size_t)b * perB;
    _Float16* sh_b = sh + (size_t)b * (size_t)U * L_DIM;

    __shared__ _Float16 ldsAh[4096];   // gathered q [u][32]
    __shared__ _Float16 ldsBh[4096];   // k [s][32]
    __shared__ int arow[128];

    const int tid = threadIdx.x;
    const int w4 = tid >> 6, lane = tid & 63;
    const int lr = lane & 15, quad = lane >> 4;
    const int wu = w4 >> 1, wn = w4 & 1;

    if (tid < 128) {
        int u = u0 + tid;
        arow[tid] = topidx[b * U + (u < U ? u : U - 1)];
    }
    __syncthreads();

    f32x4 acc[4][4] = {};
    const int qsw = (quad ^ ((lr >> 1) & 3)) * 8;

    for (int k0 = 0; k0 < 512; k0 += 32) {
        #pragma unroll
        for (int t = 0; t < 2; t++) {
            int c = w4 * 128 + t * 64 + lane;
            int row = c >> 2, part = (c & 3) ^ ((row >> 1) & 3);
            size_t go = (size_t)arow[row] * 512 + k0 + part * 8;
            size_t ko = (size_t)(s0 + row) * 512 + k0 + part * 8;
            int base = (w4 * 128 + t * 64) * 8;
            gld16(qh_b + go, ldsAh + base);
            gld16(kh_b + ko, ldsBh + base);
        }
        __syncthreads();

        half8 fAh[4];
        #pragma unroll
        for (int i = 0; i < 4; i++) {
            int u = wu * 64 + i * 16 + lr;
            fAh[i] = *(const half8*)(ldsAh + u * 32 + qsw);
        }
        #pragma unroll
        for (int j = 0; j < 4; j++) {
            int s = wn * 64 + j * 16 + lr;
            half8 fBh = *(const half8*)(ldsBh + s * 32 + qsw);
            #pragma unroll
            for (int i = 0; i < 4; i++)
                acc[i][j] = __builtin_amdgcn_mfma_f32_16x16x32_f16(fAh[i], fBh, acc[i][j], 0, 0, 0);
        }
        __syncthreads();
    }

    const float scale = 0.044194173824159216f;   // 1/sqrt(512)
    #pragma unroll
    for (int i = 0; i < 4; i++) {
        #pragma unroll
        for (int r = 0; r < 4; r++) {
            int u = u0 + wu * 64 + i * 16 + quad * 4 + r;
            if (u < U) {
                #pragma unroll
                for (int j = 0; j < 4; j++) {
                    int s = s0 + wn * 64 + j * 16 + lr;
                    sh_b[(size_t)u * L_DIM + s] = (_Float16)(acc[i][j][r] * scale);
                }
            }
        }
    }
}

// ---------------------------------------------------------------------------
// Row softmax over 4096, fp16 in/out (in place). grid (B*U), block 256
// ---------------------------------------------------------------------------
__global__ __launch_bounds__(256) void softmax_h(_Float16* __restrict__ sh)
{
    _Float16* hrow = sh + (size_t)blockIdx.x * L_DIM;
    const int tid = threadIdx.x;
    float x[16];
    #pragma unroll
    for (int t = 0; t < 2; t++) {
        half8 h8 = *(const half8*)(hrow + tid * 8 + t * 2048);
        #pragma unroll
        for (int i = 0; i < 8; i++) x[t * 8 + i] = (float)h8[i];
    }
    __shared__ float red[256];
    float lm = -__builtin_inff();
    #pragma unroll
    for (int i = 0; i < 16; i++) lm = fmaxf(lm, x[i]);
    red[tid] = lm;
    __syncthreads();
    for (int o = 128; o > 0; o >>= 1) {
        if (tid < o) red[tid] = fmaxf(red[tid], red[tid + o]);
        __syncthreads();
    }
    float m = red[0];
    __syncthreads();
    float ls = 0.f;
    #pragma unroll
    for (int i = 0; i < 16; i++) { x[i] = __expf(x[i] - m); ls += x[i]; }
    red[tid] = ls;
    __syncthreads();
    for (int o = 128; o > 0; o >>= 1) {
        if (tid < o) red[tid] += red[tid + o];
        __syncthreads();
    }
    float inv = 1.f / red[0];
    #pragma unroll
    for (int t = 0; t < 2; t++) {
        half8 h8;
        #pragma unroll
        for (int i = 0; i < 8; i++) h8[i] = (_Float16)(x[t * 8 + i] * inv);
        *(half8*)(hrow + tid * 8 + t * 2048) = h8;
    }
}

// ---------------------------------------------------------------------------
// upd via SINGLE fp16 MFMA, K-split x4, atomic accumulate into zeroed rows.
// grid: ((U+127)/128 u-tiles, 4 dd-tiles, 16*KSPLIT), block 256
// ---------------------------------------------------------------------------
__global__ __launch_bounds__(256) void upd_mfma(
    const _Float16* __restrict__ sh, const _Float16* __restrict__ vh,
    const int* __restrict__ topidx, float* __restrict__ out, int U)
{
    const int zz = blockIdx.z;
    const int b = zz >> 2, ks = zz & 3;
    const int n0 = blockIdx.y * 128;
    const int u0 = blockIdx.x * 128;
    const size_t perB = (size_t)D_DIM * L_DIM;
    const _Float16* ah_b = sh + (size_t)b * (size_t)U * L_DIM;
    const _Float16* vh_b = vh + (size_t)b * perB;

    __shared__ _Float16 ldsAh[4096];   // attn [u][32]
    __shared__ _Float16 ldsBh[4096];   // vT   [dd][32] (chunk-swizzled)

    const int tid = threadIdx.x;
    const int w4 = tid >> 6, lane = tid & 63;
    const int lr = lane & 15, quad = lane >> 4;
    const int wu = w4 >> 1, wd = w4 & 1;

    const int part = tid & 15, spair = tid >> 4;
    const int s_b = spair * 2;
    const int colw = ((spair >> 2) + part) & 3;
    const int so2 = (s_b & 7);

    f32x4 acc[4][4] = {};
    const int qsw = (quad ^ ((lr >> 1) & 3)) * 8;

    const int kbeg = ks * (L_DIM / KSPLIT);
    const int kend = kbeg + (L_DIM / KSPLIT);
    for (int k0 = kbeg; k0 < kend; k0 += 32) {
        #pragma unroll
        for (int t = 0; t < 2; t++) {
            int c = w4 * 128 + t * 64 + lane;
            int u = c >> 2, pt = (c & 3) ^ ((u >> 1) & 3);
            int urow = u0 + u; if (urow >= U) urow = U - 1;
            size_t ao = (size_t)urow * L_DIM + k0 + pt * 8;
            int base = (w4 * 128 + t * 64) * 8;
            gld16(ah_b + ao, ldsAh + base);
        }
        {
            const _Float16* s0p = vh_b + (size_t)(k0 + s_b) * 512 + n0 + part * 8;
            const _Float16* s1p = s0p + 512;
            ushort8 a0 = *(const ushort8*)s0p;
            ushort8 a1 = *(const ushort8*)s1p;
            #pragma unroll
            for (int t = 0; t < 8; t++) {
                int dd = part * 8 + t;
                unsigned int ph = (unsigned int)a0[t] | ((unsigned int)a1[t] << 16);
                *(unsigned int*)(ldsBh + dd * 32 + colw * 8 + so2) = ph;
            }
        }
        __syncthreads();

        half8 fAh[4];
        #pragma unroll
        for (int i = 0; i < 4; i++) {
            int u = wu * 64 + i * 16 + lr;
            fAh[i] = *(const half8*)(ldsAh + u * 32 + qsw);
        }
        #pragma unroll
        for (int j = 0; j < 4; j++) {
            int dd = wd * 64 + j * 16 + lr;
            int col = (quad + (dd >> 3)) & 3;
            half8 fBh = *(const half8*)(ldsBh + dd * 32 + col * 8);
            #pragma unroll
            for (int i = 0; i < 4; i++)
                acc[i][j] = __builtin_amdgcn_mfma_f32_16x16x32_f16(fAh[i], fBh, acc[i][j], 0, 0, 0);
        }
        __syncthreads();
    }

    #pragma unroll
    for (int i = 0; i < 4; i++) {
        #pragma unroll
        for (int r = 0; r < 4; r++) {
            int u = u0 + wu * 64 + i * 16 + quad * 4 + r;
            if (u < U) {
                int lrow = topidx[b * U + u];
                #pragma unroll
                for (int j = 0; j < 4; j++) {
                    int dd = n0 + wd * 64 + j * 16 + lr;
                    unsafeAtomicAdd(&out[(size_t)b * perB + (size_t)lrow * 512 + dd],
                                    acc[i][j][r]);
                }
            }
        }
    }
}

// ---------------------------------------------------------------------------
extern "C" void kernel_launch(void* const* d_in, const int* in_sizes, int n_in,
                              void* d_out, int out_size, void* d_ws, size_t ws_size,
                              hipStream_t stream)
{
    const float* x1 = (const float*)d_in[0];
    const float* x2 = (const float*)d_in[1];
    const float* Wq = (const float*)d_in[2];
    const float* bq = (const float*)d_in[3];
    const float* Wk = (const float*)d_in[4];
    const float* bk = (const float*)d_in[5];
    const float* Wv = (const float*)d_in[6];
    const float* bv = (const float*)d_in[7];
    const int*  idx = (const int*)d_in[8];
    const int U = in_sizes[8];            // 450
    const int nst = (U + 127) / 128;      // 4

    float* out = (float*)d_out;

    const size_t perB = (size_t)D_DIM * L_DIM;          // 2,097,152
    const size_t tenH = (size_t)BATCH * perB;           // 33,554,432 halves
    _Float16* qh = (_Float16*)d_ws;
    _Float16* ql = qh + tenH;
    _Float16* kh = ql + tenH;
    _Float16* kl = kh + tenH;
    _Float16* vh = kl + tenH;
    float* S = (float*)(vh + tenH);                     // union region (~202 MB)

    // proj-phase aliases inside S:
    _Float16* XTh = (_Float16*)S;
    _Float16* XTl = XTh + (size_t)8 * L_DIM * 512;
    _Float16* Wh  = XTl + (size_t)8 * L_DIM * 512;
    _Float16* Wl  = Wh + (size_t)3 * 512 * 512;

    // post-proj aliases inside S:
    _Float16* sh = (_Float16*)S;
    float* vmean = (float*)(sh + (size_t)BATCH * (size_t)U * L_DIM);
    float* partU = vmean + (size_t)BATCH * D_DIM;       // 2 MB scratch window
    float* vpart = partU;                               // vmean partials (1 MB)
    float* Mmax  = partU;                               // then qks partials (2 MB)
    float* Msum  = Mmax + (size_t)BATCH * nst * L_DIM;
    int* topidx  = (int*)(partU + (size_t)2 * BATCH * 4 * L_DIM);

    // 1. split W
    convert_w<<<dim3(1024, 3), 256, 0, stream>>>(Wq, Wk, Wv, Wh, Wl);

    // 2. projections (two 8-batch phases): q/k hi+lo (x3), v hi only (x1)
    for (int phase = 0; phase < 2; phase++) {
        convert_x<<<dim3(64, 8, 8), 256, 0, stream>>>(x1, x2, XTh, XTl, phase);
        proj_mfma_qk<<<dim3(L_DIM / 128, D_DIM / 128, 8 * 2), 256, 0, stream>>>(
            Wh, Wl, XTh, XTl, bq, bk, qh, ql, kh, kl, phase);
        proj_mfma_v<<<dim3(L_DIM / 128, D_DIM / 128, 8), 256, 0, stream>>>(
            Wh, XTh, bv, vh, phase);
    }

    // 3. v mean + output fill
    vmean_partial<<<dim3(32, BATCH), 512, 0, stream>>>(vh, vpart);
    vmean_reduce<<<BATCH, 512, 0, stream>>>(vpart, vmean);
    fill_out<<<BATCH * 64, 256, 0, stream>>>(vmean, out);

    // 4. sampled QK^T partials (s-tile split) + top-U select
    qks_mfma<<<dim3(L_DIM / 128, nst, BATCH), 256, 0, stream>>>(
        qh, ql, kh, kl, idx, Mmax, Msum, U, nst);
    topk_select<<<BATCH, 512, 0, stream>>>(Mmax, Msum, topidx, U, nst);

    // 5. scores (fp16), softmax, zero selected rows, attn @ V atomic scatter
    const int utiles = (U + 127) / 128;
    scores_mfma<<<dim3(L_DIM / 128, utiles, BATCH), 256, 0, stream>>>(
        qh, kh, topidx, sh, U);
    softmax_h<<<BATCH * U, 256, 0, stream>>>(sh);
    zero_sel<<<dim3(U, BATCH), 256, 0, stream>>>(topidx, out, U);
    upd_mfma<<<dim3(utiles, D_DIM / 128, BATCH * KSPLIT), 256, 0, stream>>>(
        sh, vh, topidx, out, U);
}

// Round 7
// 878.734 us; speedup vs baseline: 1.0571x; 1.0021x over previous
//
#include <hip/hip_runtime.h>
#include <cstdint>
#include <cstddef>

#define L_DIM 4096
#define D_DIM 512
#define CIN   256
#define BATCH 16
#define KSPLIT 4

typedef _Float16 half8 __attribute__((ext_vector_type(8)));
typedef unsigned short ushort8 __attribute__((ext_vector_type(8)));
typedef float f32x4 __attribute__((ext_vector_type(4)));

__device__ __forceinline__ void gld16(const _Float16* g, _Float16* l) {
    __builtin_amdgcn_global_load_lds(
        (const __attribute__((address_space(1))) unsigned int*)g,
        (__attribute__((address_space(3))) unsigned int*)l,
        16, 0, 0);
}

// ---------------------------------------------------------------------------
// Split W (3 x 512x512 fp32) into fp16 hi/lo. grid (1024,3), block 256
// ---------------------------------------------------------------------------
__global__ __launch_bounds__(256) void convert_w(
    const float* __restrict__ Wq, const float* __restrict__ Wk,
    const float* __restrict__ Wv,
    _Float16* __restrict__ Wh, _Float16* __restrict__ Wl)
{
    const int w = blockIdx.y;
    const float* src = (w == 0) ? Wq : (w == 1) ? Wk : Wv;
    int i = blockIdx.x * 256 + threadIdx.x;
    float xv = src[i];
    _Float16 hi = (_Float16)xv;
    Wh[(size_t)w * 262144 + i] = hi;
    Wl[(size_t)w * 262144 + i] = (_Float16)(xv - (float)hi);
}

// ---------------------------------------------------------------------------
// Transpose + split X. Per phase 8 batches. grid (64, 8, 8), block 256.
// Vectorized: float4 global loads (16 B/lane), half8 hi/lo stores (16 B/lane).
// Same value mapping as the scalar version: XT[s][c] = split(x[c][s]).
// ---------------------------------------------------------------------------
__global__ __launch_bounds__(256) void convert_x(
    const float* __restrict__ x1, const float* __restrict__ x2,
    _Float16* __restrict__ XTh, _Float16* __restrict__ XTl, int phase)
{
    const int bb = blockIdx.z;
    const int b = phase * 8 + bb;
    const int s0 = blockIdx.x * 64;
    const int c0 = blockIdx.y * 64;
    __shared__ float t[64][65];              // t[channel][spatial]
    const int tid = threadIdx.x;
    const float* src = (c0 < CIN)
        ? (x1 + (size_t)b * CIN * L_DIM + (size_t)c0 * L_DIM)
        : (x2 + (size_t)b * CIN * L_DIM + (size_t)(c0 - CIN) * L_DIM);

    // load: 64 ch x 64 sp tile; each thread 4x float4
    {
        const int sy4 = (tid & 15) * 4;      // spatial offset
        const int clb = tid >> 4;            // channel base 0..15
        #pragma unroll
        for (int r = 0; r < 4; r++) {
            int cl = clb + r * 16;
            float4 v = *(const float4*)&src[(size_t)cl * L_DIM + s0 + sy4];
            t[cl][sy4 + 0] = v.x;
            t[cl][sy4 + 1] = v.y;
            t[cl][sy4 + 2] = v.z;
            t[cl][sy4 + 3] = v.w;
        }
    }
    __syncthreads();

    _Float16* outh = XTh + (size_t)bb * L_DIM * 512 + (size_t)s0 * 512 + c0;
    _Float16* outl = XTl + (size_t)bb * L_DIM * 512 + (size_t)s0 * 512 + c0;
    {
        const int ch0 = (tid & 7) * 8;       // channel offset (8 per thread)
        const int slb = tid >> 3;            // spatial base 0..31
        #pragma unroll
        for (int r = 0; r < 2; r++) {
            int sl = slb + r * 32;
            half8 h, l;
            #pragma unroll
            for (int i = 0; i < 8; i++) {
                float xv = t[ch0 + i][sl];
                _Float16 hi = (_Float16)xv;
                h[i] = hi;
                l[i] = (_Float16)(xv - (float)hi);
            }
            *(half8*)&outh[(size_t)sl * 512 + ch0] = h;
            *(half8*)&outl[(size_t)sl * 512 + ch0] = l;
        }
    }
}

// ---------------------------------------------------------------------------
// q/k projection via fp16x3 MFMA, hi+lo outputs, swizzled LDS.
// grid: (32, 4, 16), block 256
// ---------------------------------------------------------------------------
__global__ __launch_bounds__(256) void proj_mfma_qk(
    const _Float16* __restrict__ Wh, const _Float16* __restrict__ Wl,
    const _Float16* __restrict__ XTh, const _Float16* __restrict__ XTl,
    const float* __restrict__ bq, const float* __restrict__ bk,
    _Float16* __restrict__ qh, _Float16* __restrict__ ql,
    _Float16* __restrict__ kh, _Float16* __restrict__ kl,
    int phase)
{
    const int z = blockIdx.z;
    const int bb = z >> 1, w = z & 1;
    const int b = phase * 8 + bb;
    const _Float16* Ah_g = Wh + (size_t)w * 262144;
    const _Float16* Al_g = Wl + (size_t)w * 262144;
    const _Float16* Bh_g = XTh + (size_t)bb * ((size_t)L_DIM * 512);
    const _Float16* Bl_g = XTl + (size_t)bb * ((size_t)L_DIM * 512);
    const float* bias = (w == 0) ? bq : bk;
    _Float16* outh = ((w == 0) ? qh : kh) + (size_t)b * ((size_t)D_DIM * L_DIM);
    _Float16* outl = ((w == 0) ? ql : kl) + (size_t)b * ((size_t)D_DIM * L_DIM);

    const int m0 = blockIdx.y * 128;
    const int n0 = blockIdx.x * 128;

    __shared__ _Float16 lds[4 * 128 * 32];
    _Float16* ldsA_h = lds;
    _Float16* ldsA_l = lds + 4096;
    _Float16* ldsB_h = lds + 8192;
    _Float16* ldsB_l = lds + 12288;

    const int tid = threadIdx.x;
    const int w4 = tid >> 6, lane = tid & 63;
    const int lr = lane & 15, quad = lane >> 4;
    const int wr = w4 >> 1, wc = w4 & 1;

    f32x4 acc[4][4] = {};

    const int q1 = w4 * 128 + lane, q2 = q1 + 64;
    const int r1 = q1 >> 2, c41 = (q1 & 3) ^ ((r1 >> 1) & 3);
    const int r2 = q2 >> 2, c42 = (q2 & 3) ^ ((r2 >> 1) & 3);

    const _Float16* pAh1 = Ah_g + (size_t)(m0 + r1) * 512 + c41 * 8;
    const _Float16* pAh2 = Ah_g + (size_t)(m0 + r2) * 512 + c42 * 8;
    const _Float16* pAl1 = Al_g + (size_t)(m0 + r1) * 512 + c41 * 8;
    const _Float16* pAl2 = Al_g + (size_t)(m0 + r2) * 512 + c42 * 8;
    const _Float16* pBh1 = Bh_g + (size_t)(n0 + r1) * 512 + c41 * 8;
    const _Float16* pBh2 = Bh_g + (size_t)(n0 + r2) * 512 + c42 * 8;
    const _Float16* pBl1 = Bl_g + (size_t)(n0 + r1) * 512 + c41 * 8;
    const _Float16* pBl2 = Bl_g + (size_t)(n0 + r2) * 512 + c42 * 8;

    _Float16* d1 = (_Float16*)(lds) + (size_t)(w4 * 128) * 8;
    _Float16* d2 = (_Float16*)(lds) + (size_t)(w4 * 128 + 64) * 8;

    const int qsw = (quad ^ ((lr >> 1) & 3)) * 8;

    for (int k0 = 0; k0 < 512; k0 += 32) {
        if (k0) __syncthreads();
        gld16(pAh1 + k0, d1);
        gld16(pAh2 + k0, d2);
        gld16(pAl1 + k0, d1 + 4096);
        gld16(pAl2 + k0, d2 + 4096);
        gld16(pBh1 + k0, d1 + 8192);
        gld16(pBh2 + k0, d2 + 8192);
        gld16(pBl1 + k0, d1 + 12288);
        gld16(pBl2 + k0, d2 + 12288);
        __syncthreads();

        half8 fAh[4], fAl[4];
        #pragma unroll
        for (int i = 0; i < 4; i++) {
            int m = wr * 64 + i * 16 + lr;
            fAh[i] = *(const half8*)(ldsA_h + m * 32 + qsw);
            fAl[i] = *(const half8*)(ldsA_l + m * 32 + qsw);
        }
        #pragma unroll
        for (int j = 0; j < 4; j++) {
            int n = wc * 64 + j * 16 + lr;
            half8 fBh = *(const half8*)(ldsB_h + n * 32 + qsw);
            half8 fBl = *(const half8*)(ldsB_l + n * 32 + qsw);
            #pragma unroll
            for (int i = 0; i < 4; i++) {
                acc[i][j] = __builtin_amdgcn_mfma_f32_16x16x32_f16(fAh[i], fBh, acc[i][j], 0, 0, 0);
                acc[i][j] = __builtin_amdgcn_mfma_f32_16x16x32_f16(fAl[i], fBh, acc[i][j], 0, 0, 0);
                acc[i][j] = __builtin_amdgcn_mfma_f32_16x16x32_f16(fAh[i], fBl, acc[i][j], 0, 0, 0);
            }
        }
    }

    #pragma unroll
    for (int i = 0; i < 4; i++) {
        int mg = m0 + wr * 64 + i * 16 + quad * 4;
        #pragma unroll
        for (int r = 0; r < 4; r++) {
            float bvv = bias[mg + r];
            #pragma unroll
            for (int j = 0; j < 4; j++) {
                int ng = n0 + wc * 64 + j * 16 + lr;
                float val = acc[i][j][r] + bvv;
                _Float16 hi = (_Float16)val;
                size_t off = (size_t)(mg + r) * L_DIM + ng;
                outh[off] = hi;
                outl[off] = (_Float16)(val - (float)hi);
            }
        }
    }
}

// ---------------------------------------------------------------------------
// V projection: hi-only single-MFMA GEMM. grid: (32, 4, 8), block 256
// ---------------------------------------------------------------------------
__global__ __launch_bounds__(256) void proj_mfma_v(
    const _Float16* __restrict__ Wh, const _Float16* __restrict__ XTh,
    const float* __restrict__ bv, _Float16* __restrict__ vh, int phase)
{
    const int bb = blockIdx.z;
    const int b = phase * 8 + bb;
    const _Float16* Ah_g = Wh + (size_t)2 * 262144;
    const _Float16* Bh_g = XTh + (size_t)bb * ((size_t)L_DIM * 512);
    _Float16* outh = vh + (size_t)b * ((size_t)D_DIM * L_DIM);

    const int m0 = blockIdx.y * 128;
    const int n0 = blockIdx.x * 128;

    __shared__ _Float16 lds[2 * 128 * 32];
    _Float16* ldsA_h = lds;
    _Float16* ldsB_h = lds + 4096;

    const int tid = threadIdx.x;
    const int w4 = tid >> 6, lane = tid & 63;
    const int lr = lane & 15, quad = lane >> 4;
    const int wr = w4 >> 1, wc = w4 & 1;

    f32x4 acc[4][4] = {};

    const int q1 = w4 * 128 + lane, q2 = q1 + 64;
    const int r1 = q1 >> 2, c41 = (q1 & 3) ^ ((r1 >> 1) & 3);
    const int r2 = q2 >> 2, c42 = (q2 & 3) ^ ((r2 >> 1) & 3);

    const _Float16* pAh1 = Ah_g + (size_t)(m0 + r1) * 512 + c41 * 8;
    const _Float16* pAh2 = Ah_g + (size_t)(m0 + r2) * 512 + c42 * 8;
    const _Float16* pBh1 = Bh_g + (size_t)(n0 + r1) * 512 + c41 * 8;
    const _Float16* pBh2 = Bh_g + (size_t)(n0 + r2) * 512 + c42 * 8;

    _Float16* d1 = (_Float16*)(lds) + (size_t)(w4 * 128) * 8;
    _Float16* d2 = (_Float16*)(lds) + (size_t)(w4 * 128 + 64) * 8;

    const int qsw = (quad ^ ((lr >> 1) & 3)) * 8;

    for (int k0 = 0; k0 < 512; k0 += 32) {
        if (k0) __syncthreads();
        gld16(pAh1 + k0, d1);
        gld16(pAh2 + k0, d2);
        gld16(pBh1 + k0, d1 + 4096);
        gld16(pBh2 + k0, d2 + 4096);
        __syncthreads();

        half8 fAh[4];
        #pragma unroll
        for (int i = 0; i < 4; i++) {
            int m = wr * 64 + i * 16 + lr;
            fAh[i] = *(const half8*)(ldsA_h + m * 32 + qsw);
        }
        #pragma unroll
        for (int j = 0; j < 4; j++) {
            int n = wc * 64 + j * 16 + lr;
            half8 fBh = *(const half8*)(ldsB_h + n * 32 + qsw);
            #pragma unroll
            for (int i = 0; i < 4; i++)
                acc[i][j] = __builtin_amdgcn_mfma_f32_16x16x32_f16(fAh[i], fBh, acc[i][j], 0, 0, 0);
        }
    }

    #pragma unroll
    for (int i = 0; i < 4; i++) {
        int mg = m0 + wr * 64 + i * 16 + quad * 4;
        #pragma unroll
        for (int r = 0; r < 4; r++) {
            float bvv = bv[mg + r];
            #pragma unroll
            for (int j = 0; j < 4; j++) {
                int ng = n0 + wc * 64 + j * 16 + lr;
                outh[(size_t)(mg + r) * L_DIM + ng] = (_Float16)(acc[i][j][r] + bvv);
            }
        }
    }
}

// ---------------------------------------------------------------------------
// qks via fp16x3 MFMA, one s-tile per block, partial max/sum out.
// redm/reds ALIAS the staging buffers (dead after the K-loop; the loop-bottom
// __syncthreads seals all staging reads) -> LDS 41.5 KB -> 32.5 KB,
// 3 -> 4 blocks/CU.
// grid: (32 l-tiles, nst s-tiles, 16 b), block 256
// ---------------------------------------------------------------------------
__global__ __launch_bounds__(256) void qks_mfma(
    const _Float16* __restrict__ qh, const _Float16* __restrict__ ql,
    const _Float16* __restrict__ kh, const _Float16* __restrict__ kl,
    const int* __restrict__ idx_sample,
    float* __restrict__ Mmax, float* __restrict__ Msum, int U, int nst)
{
    const int b = blockIdx.z;
    const int stile = blockIdx.y;
    const int l0 = blockIdx.x * 128;
    const int s0 = stile * 128;
    const size_t perB = (size_t)D_DIM * L_DIM;
    const _Float16* qh_b = qh + (size_t)b * perB;
    const _Float16* ql_b = ql + (size_t)b * perB;
    const _Float16* kh_b = kh + (size_t)b * perB;
    const _Float16* kl_b = kl + (size_t)b * perB;

    __shared__ _Float16 ldsAh[4096], ldsAl[4096];   // gathered k [s][32]
    __shared__ _Float16 ldsBh[4096], ldsBl[4096];   // q [l][32]
    __shared__ int sidx[128];
    float* redm = (float*)ldsAh;   // 8x128 f32 = 4 KB, aliases dead staging
    float* reds = (float*)ldsBh;   // 8x128 f32 = 4 KB

    const int tid = threadIdx.x;
    const int w4 = tid >> 6, lane = tid & 63;
    const int lr = lane & 15, quad = lane >> 4;
    const int ws = w4 >> 1, wl = w4 & 1;

    if (tid < 128) {
        int s = s0 + tid;
        sidx[tid] = (s < U) ? idx_sample[s] : idx_sample[0];
    }
    __syncthreads();

    f32x4 acc[4][4] = {};
    const int qsw = (quad ^ ((lr >> 1) & 3)) * 8;

    for (int k0 = 0; k0 < 512; k0 += 32) {
        #pragma unroll
        for (int t = 0; t < 2; t++) {
            int c = w4 * 128 + t * 64 + lane;
            int row = c >> 2, part = (c & 3) ^ ((row >> 1) & 3);
            int krow = sidx[row];
            size_t go = (size_t)krow * 512 + k0 + part * 8;
            size_t qo = (size_t)(l0 + row) * 512 + k0 + part * 8;
            int base = (w4 * 128 + t * 64) * 8;
            gld16(kh_b + go, ldsAh + base);
            gld16(kl_b + go, ldsAl + base);
            gld16(qh_b + qo, ldsBh + base);
            gld16(ql_b + qo, ldsBl + base);
        }
        __syncthreads();

        half8 fAh[4], fAl[4];
        #pragma unroll
        for (int i = 0; i < 4; i++) {
            int s = ws * 64 + i * 16 + lr;
            fAh[i] = *(const half8*)(ldsAh + s * 32 + qsw);
            fAl[i] = *(const half8*)(ldsAl + s * 32 + qsw);
        }
        #pragma unroll
        for (int j = 0; j < 4; j++) {
            int l = wl * 64 + j * 16 + lr;
            half8 fBh = *(const half8*)(ldsBh + l * 32 + qsw);
            half8 fBl = *(const half8*)(ldsBl + l * 32 + qsw);
            #pragma unroll
            for (int i = 0; i < 4; i++) {
                acc[i][j] = __builtin_amdgcn_mfma_f32_16x16x32_f16(fAh[i], fBh, acc[i][j], 0, 0, 0);
                acc[i][j] = __builtin_amdgcn_mfma_f32_16x16x32_f16(fAl[i], fBh, acc[i][j], 0, 0, 0);
                acc[i][j] = __builtin_amdgcn_mfma_f32_16x16x32_f16(fAh[i], fBl, acc[i][j], 0, 0, 0);
            }
        }
        __syncthreads();
    }

    float runmax[4], runsum[4];
    #pragma unroll
    for (int j = 0; j < 4; j++) { runmax[j] = -__builtin_inff(); runsum[j] = 0.f; }
    #pragma unroll
    for (int i = 0; i < 4; i++) {
        #pragma unroll
        for (int r = 0; r < 4; r++) {
            int sg = s0 + ws * 64 + i * 16 + quad * 4 + r;
            if (sg < U) {
                #pragma unroll
                for (int j = 0; j < 4; j++) {
                    runmax[j] = fmaxf(runmax[j], acc[i][j][r]);
                    runsum[j] += acc[i][j][r];
                }
            }
        }
    }
    #pragma unroll
    for (int j = 0; j < 4; j++) {
        int l = wl * 64 + j * 16 + lr;
        redm[(ws * 4 + quad) * 128 + l] = runmax[j];
        reds[(ws * 4 + quad) * 128 + l] = runsum[j];
    }
    __syncthreads();
    if (tid < 128) {
        float gm = -__builtin_inff(), gs = 0.f;
        #pragma unroll
        for (int t = 0; t < 8; t++) { gm = fmaxf(gm, redm[t * 128 + tid]); gs += reds[t * 128 + tid]; }
        size_t o = ((size_t)b * nst + stile) * L_DIM + l0 + tid;
        Mmax[o] = gm;
        Msum[o] = gs;
    }
}

// ---------------------------------------------------------------------------
// Per-batch top-U: reduce partials -> M, binary-search threshold on key bits,
// compact indices (set semantics). grid (B), block 512.
// ---------------------------------------------------------------------------
__global__ __launch_bounds__(512) void topk_select(
    const float* __restrict__ Mmax, const float* __restrict__ Msum,
    int* __restrict__ topidx, int U, int nst)
{
    const int b = blockIdx.x;
    const int tid = threadIdx.x;
    __shared__ int wcnt[8];
    __shared__ int basec;

    unsigned mykey[8];
    #pragma unroll
    for (int t = 0; t < 8; t++) {
        int l = t * 512 + tid;
        float gm = -__builtin_inff(), gs = 0.f;
        for (int st = 0; st < nst; st++) {
            size_t o = ((size_t)b * nst + st) * L_DIM + l;
            gm = fmaxf(gm, Mmax[o]);
            gs += Msum[o];
        }
        float M = gm - gs * (1.f / (float)L_DIM);
        unsigned bits = __float_as_uint(M);
        mykey[t] = (bits & 0x80000000u) ? ~bits : (bits | 0x80000000u);
    }
    if (tid == 0) basec = 0;

    const int wv = tid >> 6, lane = tid & 63;
    unsigned lo = 0u, hi = 0xFFFFFFFFu;
    while (lo < hi) {
        unsigned hl = hi - lo;
        unsigned mid = lo + (hl >> 1) + (hl & 1u);   // ceil midpoint, overflow-safe
        int c = 0;
        #pragma unroll
        for (int t = 0; t < 8; t++) c += (mykey[t] >= mid) ? 1 : 0;
        #pragma unroll
        for (int o = 32; o > 0; o >>= 1) c += __shfl_down(c, o, 64);
        if (lane == 0) wcnt[wv] = c;
        __syncthreads();
        int total = 0;
        #pragma unroll
        for (int i = 0; i < 8; i++) total += wcnt[i];
        if (total >= U) lo = mid; else hi = mid - 1;
        __syncthreads();
    }
    #pragma unroll
    for (int t = 0; t < 8; t++) {
        if (mykey[t] >= lo) {
            int pos = atomicAdd(&basec, 1);
            if (pos < U) topidx[b * U + pos] = t * 512 + tid;
        }
    }
}

// ---------------------------------------------------------------------------
// v mean from v_h
// ---------------------------------------------------------------------------
__global__ __launch_bounds__(512) void vmean_partial(
    const _Float16* __restrict__ vh, float* __restrict__ partial)
{
    const int ch = blockIdx.x, b = blockIdx.y;
    const int d = threadIdx.x;
    const _Float16* vhb = vh + (size_t)b * ((size_t)D_DIM * L_DIM);
    float acc = 0.f;
    const int lbeg = ch * 128;
    for (int l = lbeg; l < lbeg + 128; l++)
        acc += (float)vhb[(size_t)l * D_DIM + d];
    partial[((size_t)b * 32 + ch) * D_DIM + d] = acc;
}

__global__ __launch_bounds__(512) void vmean_reduce(const float* __restrict__ partial,
                                                    float* __restrict__ vmean)
{
    const int b = blockIdx.x;
    const int d = threadIdx.x;
    float acc = 0.f;
    for (int ch = 0; ch < 32; ch++) acc += partial[((size_t)b * 32 + ch) * D_DIM + d];
    vmean[b * D_DIM + d] = acc * (1.f / (float)L_DIM);
}

__global__ __launch_bounds__(256) void fill_out(const float* __restrict__ vmean,
                                                float* __restrict__ out)
{
    const int z = blockIdx.x;
    const int b = z >> 6, lch = z & 63;
    __shared__ float vm[512];
    vm[threadIdx.x] = vmean[b * 512 + threadIdx.x];
    vm[threadIdx.x + 256] = vmean[b * 512 + threadIdx.x + 256];
    __syncthreads();
    float* op = out + (size_t)b * ((size_t)D_DIM * L_DIM) + (size_t)lch * 64 * 512;
    #pragma unroll
    for (int it = 0; it < 32; it++) {
        int flat = (threadIdx.x + it * 256) * 4;
        int d = flat & 511;
        float4 r = { vm[d], vm[d + 1], vm[d + 2], vm[d + 3] };
        *(float4*)&op[flat] = r;
    }
}

// Zero selected output rows ahead of atomic accumulation. grid (U, B), block 256
__global__ __launch_bounds__(256) void zero_sel(const int* __restrict__ topidx,
                                                float* __restrict__ out, int U)
{
    const int u = blockIdx.x, b = blockIdx.y;
    int row = topidx[b * U + u];
    float2 z = { 0.f, 0.f };
    *(float2*)&out[(size_t)b * ((size_t)D_DIM * L_DIM) + (size_t)row * 512
                   + threadIdx.x * 2] = z;
}

// ---------------------------------------------------------------------------
// scores via SINGLE fp16 MFMA. grid: (32 s-tiles, u-tiles, 16 b), block 256
// ---------------------------------------------------------------------------
__global__ __launch_bounds__(256) void scores_mfma(
    const _Float16* __restrict__ qh, const _Float16* __restrict__ kh,
    const int* __restrict__ topidx,
    _Float16* __restrict__ sh, int U)
{
    const int b = blockIdx.z;
    const int s0 = blockIdx.x * 128;
    const int u0 = blockIdx.y * 128;
    const size_t perB = (size_t)D_DIM * L_DIM;
    const _Float16* qh_b = qh + (size_t)b * perB;
    const _Float16* kh_b = kh + (size_t)b * perB;
    _Float16* sh_b = sh + (size_t)b * (size_t)U * L_DIM;

    __shared__ _Float16 ldsAh[4096];   // gathered q [u][32]
    __shared__ _Float16 ldsBh[4096];   // k [s][32]
    __shared__ int arow[128];

    const int tid = threadIdx.x;
    const int w4 = tid >> 6, lane = tid & 63;
    const int lr = lane & 15, quad = lane >> 4;
    const int wu = w4 >> 1, wn = w4 & 1;

    if (tid < 128) {
        int u = u0 + tid;
        arow[tid] = topidx[b * U + (u < U ? u : U - 1)];
    }
    __syncthreads();

    f32x4 acc[4][4] = {};
    const int qsw = (quad ^ ((lr >> 1) & 3)) * 8;

    for (int k0 = 0; k0 < 512; k0 += 32) {
        #pragma unroll
        for (int t = 0; t < 2; t++) {
            int c = w4 * 128 + t * 64 + lane;
            int row = c >> 2, part = (c & 3) ^ ((row >> 1) & 3);
            size_t go = (size_t)arow[row] * 512 + k0 + part * 8;
            size_t ko = (size_t)(s0 + row) * 512 + k0 + part * 8;
            int base = (w4 * 128 + t * 64) * 8;
            gld16(qh_b + go, ldsAh + base);
            gld16(kh_b + ko, ldsBh + base);
        }
        __syncthreads();

        half8 fAh[4];
        #pragma unroll
        for (int i = 0; i < 4; i++) {
            int u = wu * 64 + i * 16 + lr;
            fAh[i] = *(const half8*)(ldsAh + u * 32 + qsw);
        }
        #pragma unroll
        for (int j = 0; j < 4; j++) {
            int s = wn * 64 + j * 16 + lr;
            half8 fBh = *(const half8*)(ldsBh + s * 32 + qsw);
            #pragma unroll
            for (int i = 0; i < 4; i++)
                acc[i][j] = __builtin_amdgcn_mfma_f32_16x16x32_f16(fAh[i], fBh, acc[i][j], 0, 0, 0);
        }
        __syncthreads();
    }

    const float scale = 0.044194173824159216f;   // 1/sqrt(512)
    #pragma unroll
    for (int i = 0; i < 4; i++) {
        #pragma unroll
        for (int r = 0; r < 4; r++) {
            int u = u0 + wu * 64 + i * 16 + quad * 4 + r;
            if (u < U) {
                #pragma unroll
                for (int j = 0; j < 4; j++) {
                    int s = s0 + wn * 64 + j * 16 + lr;
                    sh_b[(size_t)u * L_DIM + s] = (_Float16)(acc[i][j][r] * scale);
                }
            }
        }
    }
}

// ---------------------------------------------------------------------------
// Row softmax over 4096, fp16 in/out (in place). grid (B*U), block 256
// ---------------------------------------------------------------------------
__global__ __launch_bounds__(256) void softmax_h(_Float16* __restrict__ sh)
{
    _Float16* hrow = sh + (size_t)blockIdx.x * L_DIM;
    const int tid = threadIdx.x;
    float x[16];
    #pragma unroll
    for (int t = 0; t < 2; t++) {
        half8 h8 = *(const half8*)(hrow + tid * 8 + t * 2048);
        #pragma unroll
        for (int i = 0; i < 8; i++) x[t * 8 + i] = (float)h8[i];
    }
    __shared__ float red[256];
    float lm = -__builtin_inff();
    #pragma unroll
    for (int i = 0; i < 16; i++) lm = fmaxf(lm, x[i]);
    red[tid] = lm;
    __syncthreads();
    for (int o = 128; o > 0; o >>= 1) {
        if (tid < o) red[tid] = fmaxf(red[tid], red[tid + o]);
        __syncthreads();
    }
    float m = red[0];
    __syncthreads();
    float ls = 0.f;
    #pragma unroll
    for (int i = 0; i < 16; i++) { x[i] = __expf(x[i] - m); ls += x[i]; }
    red[tid] = ls;
    __syncthreads();
    for (int o = 128; o > 0; o >>= 1) {
        if (tid < o) red[tid] += red[tid + o];
        __syncthreads();
    }
    float inv = 1.f / red[0];
    #pragma unroll
    for (int t = 0; t < 2; t++) {
        half8 h8;
        #pragma unroll
        for (int i = 0; i < 8; i++) h8[i] = (_Float16)(x[t * 8 + i] * inv);
        *(half8*)(hrow + tid * 8 + t * 2048) = h8;
    }
}

// ---------------------------------------------------------------------------
// upd via SINGLE fp16 MFMA, K-split x4, atomic accumulate into zeroed rows.
// grid: ((U+127)/128 u-tiles, 4 dd-tiles, 16*KSPLIT), block 256
// ---------------------------------------------------------------------------
__global__ __launch_bounds__(256) void upd_mfma(
    const _Float16* __restrict__ sh, const _Float16* __restrict__ vh,
    const int* __restrict__ topidx, float* __restrict__ out, int U)
{
    const int zz = blockIdx.z;
    const int b = zz >> 2, ks = zz & 3;
    const int n0 = blockIdx.y * 128;
    const int u0 = blockIdx.x * 128;
    const size_t perB = (size_t)D_DIM * L_DIM;
    const _Float16* ah_b = sh + (size_t)b * (size_t)U * L_DIM;
    const _Float16* vh_b = vh + (size_t)b * perB;

    __shared__ _Float16 ldsAh[4096];   // attn [u][32]
    __shared__ _Float16 ldsBh[4096];   // vT   [dd][32] (chunk-swizzled)

    const int tid = threadIdx.x;
    const int w4 = tid >> 6, lane = tid & 63;
    const int lr = lane & 15, quad = lane >> 4;
    const int wu = w4 >> 1, wd = w4 & 1;

    const int part = tid & 15, spair = tid >> 4;
    const int s_b = spair * 2;
    const int colw = ((spair >> 2) + part) & 3;
    const int so2 = (s_b & 7);

    f32x4 acc[4][4] = {};
    const int qsw = (quad ^ ((lr >> 1) & 3)) * 8;

    const int kbeg = ks * (L_DIM / KSPLIT);
    const int kend = kbeg + (L_DIM / KSPLIT);
    for (int k0 = kbeg; k0 < kend; k0 += 32) {
        #pragma unroll
        for (int t = 0; t < 2; t++) {
            int c = w4 * 128 + t * 64 + lane;
            int u = c >> 2, pt = (c & 3) ^ ((u >> 1) & 3);
            int urow = u0 + u; if (urow >= U) urow = U - 1;
            size_t ao = (size_t)urow * L_DIM + k0 + pt * 8;
            int base = (w4 * 128 + t * 64) * 8;
            gld16(ah_b + ao, ldsAh + base);
        }
        {
            const _Float16* s0p = vh_b + (size_t)(k0 + s_b) * 512 + n0 + part * 8;
            const _Float16* s1p = s0p + 512;
            ushort8 a0 = *(const ushort8*)s0p;
            ushort8 a1 = *(const ushort8*)s1p;
            #pragma unroll
            for (int t = 0; t < 8; t++) {
                int dd = part * 8 + t;
                unsigned int ph = (unsigned int)a0[t] | ((unsigned int)a1[t] << 16);
                *(unsigned int*)(ldsBh + dd * 32 + colw * 8 + so2) = ph;
            }
        }
        __syncthreads();

        half8 fAh[4];
        #pragma unroll
        for (int i = 0; i < 4; i++) {
            int u = wu * 64 + i * 16 + lr;
            fAh[i] = *(const half8*)(ldsAh + u * 32 + qsw);
        }
        #pragma unroll
        for (int j = 0; j < 4; j++) {
            int dd = wd * 64 + j * 16 + lr;
            int col = (quad + (dd >> 3)) & 3;
            half8 fBh = *(const half8*)(ldsBh + dd * 32 + col * 8);
            #pragma unroll
            for (int i = 0; i < 4; i++)
                acc[i][j] = __builtin_amdgcn_mfma_f32_16x16x32_f16(fAh[i], fBh, acc[i][j], 0, 0, 0);
        }
        __syncthreads();
    }

    #pragma unroll
    for (int i = 0; i < 4; i++) {
        #pragma unroll
        for (int r = 0; r < 4; r++) {
            int u = u0 + wu * 64 + i * 16 + quad * 4 + r;
            if (u < U) {
                int lrow = topidx[b * U + u];
                #pragma unroll
                for (int j = 0; j < 4; j++) {
                    int dd = n0 + wd * 64 + j * 16 + lr;
                    unsafeAtomicAdd(&out[(size_t)b * perB + (size_t)lrow * 512 + dd],
                                    acc[i][j][r]);
                }
            }
        }
    }
}

// ---------------------------------------------------------------------------
extern "C" void kernel_launch(void* const* d_in, const int* in_sizes, int n_in,
                              void* d_out, int out_size, void* d_ws, size_t ws_size,
                              hipStream_t stream)
{
    const float* x1 = (const float*)d_in[0];
    const float* x2 = (const float*)d_in[1];
    const float* Wq = (const float*)d_in[2];
    const float* bq = (const float*)d_in[3];
    const float* Wk = (const float*)d_in[4];
    const float* bk = (const float*)d_in[5];
    const float* Wv = (const float*)d_in[6];
    const float* bv = (const float*)d_in[7];
    const int*  idx = (const int*)d_in[8];
    const int U = in_sizes[8];            // 450
    const int nst = (U + 127) / 128;      // 4

    float* out = (float*)d_out;

    const size_t perB = (size_t)D_DIM * L_DIM;          // 2,097,152
    const size_t tenH = (size_t)BATCH * perB;           // 33,554,432 halves
    _Float16* qh = (_Float16*)d_ws;
    _Float16* ql = qh + tenH;
    _Float16* kh = ql + tenH;
    _Float16* kl = kh + tenH;
    _Float16* vh = kl + tenH;
    float* S = (float*)(vh + tenH);                     // union region (~202 MB)

    // proj-phase aliases inside S:
    _Float16* XTh = (_Float16*)S;
    _Float16* XTl = XTh + (size_t)8 * L_DIM * 512;
    _Float16* Wh  = XTl + (size_t)8 * L_DIM * 512;
    _Float16* Wl  = Wh + (size_t)3 * 512 * 512;

    // post-proj aliases inside S:
    _Float16* sh = (_Float16*)S;
    float* vmean = (float*)(sh + (size_t)BATCH * (size_t)U * L_DIM);
    float* partU = vmean + (size_t)BATCH * D_DIM;       // 2 MB scratch window
    float* vpart = partU;                               // vmean partials (1 MB)
    float* Mmax  = partU;                               // then qks partials (2 MB)
    float* Msum  = Mmax + (size_t)BATCH * nst * L_DIM;
    int* topidx  = (int*)(partU + (size_t)2 * BATCH * 4 * L_DIM);

    // 1. split W
    convert_w<<<dim3(1024, 3), 256, 0, stream>>>(Wq, Wk, Wv, Wh, Wl);

    // 2. projections (two 8-batch phases): q/k hi+lo (x3), v hi only (x1)
    for (int phase = 0; phase < 2; phase++) {
        convert_x<<<dim3(64, 8, 8), 256, 0, stream>>>(x1, x2, XTh, XTl, phase);
        proj_mfma_qk<<<dim3(L_DIM / 128, D_DIM / 128, 8 * 2), 256, 0, stream>>>(
            Wh, Wl, XTh, XTl, bq, bk, qh, ql, kh, kl, phase);
        proj_mfma_v<<<dim3(L_DIM / 128, D_DIM / 128, 8), 256, 0, stream>>>(
            Wh, XTh, bv, vh, phase);
    }

    // 3. v mean + output fill
    vmean_partial<<<dim3(32, BATCH), 512, 0, stream>>>(vh, vpart);
    vmean_reduce<<<BATCH, 512, 0, stream>>>(vpart, vmean);
    fill_out<<<BATCH * 64, 256, 0, stream>>>(vmean, out);

    // 4. sampled QK^T partials (s-tile split) + top-U select
    qks_mfma<<<dim3(L_DIM / 128, nst, BATCH), 256, 0, stream>>>(
        qh, ql, kh, kl, idx, Mmax, Msum, U, nst);
    topk_select<<<BATCH, 512, 0, stream>>>(Mmax, Msum, topidx, U, nst);

    // 5. scores (fp16), softmax, zero selected rows, attn @ V atomic scatter
    const int utiles = (U + 127) / 128;
    scores_mfma<<<dim3(L_DIM / 128, utiles, BATCH), 256, 0, stream>>>(
        qh, kh, topidx, sh, U);
    softmax_h<<<BATCH * U, 256, 0, stream>>>(sh);
    zero_sel<<<dim3(U, BATCH), 256, 0, stream>>>(topidx, out, U);
    upd_mfma<<<dim3(utiles, D_DIM / 128, BATCH * KSPLIT), 256, 0, stream>>>(
        sh, vh, topidx, out, U);
}